// Round 5
// baseline (209.751 us; speedup 1.0000x reference)
//
#include <hip/hip_runtime.h>

typedef __attribute__((ext_vector_type(8))) _Float16 f16x8;   // 8 fp16 = 4 VGPRs
typedef __attribute__((ext_vector_type(4))) float f32x4;

constexpr int kC  = 128;
constexpr int kCH = 64;
constexpr int kN  = 4096;
constexpr float kLog2e = 1.4426950408889634f;

__device__ __forceinline__ unsigned pkrtz(float a, float b) {
    union { __fp16 __attribute__((ext_vector_type(2))) v; unsigned u; } cv;
    cv.v = __builtin_amdgcn_cvt_pkrtz(a, b);
    return cv.u;
}

__device__ __forceinline__ float x2(float x) {        // bare v_exp_f32
    return __builtin_amdgcn_exp2f(x);
}

// direct global->LDS DMA, 16B per lane, dest = wave-uniform base + lane*16
__device__ __forceinline__ void g2l16(const unsigned short* g, unsigned short* l) {
    __builtin_amdgcn_global_load_lds(
        (const __attribute__((address_space(1))) unsigned int*)(g),
        (__attribute__((address_space(3))) unsigned int*)(l),
        16, 0, 0);
}

// ---------------------------------------------------------------------------
// Fused projection — byte-identical to R4 (control). Two slices:
//   0: tgt -> Q,G   1: ref -> K,V. 2 token-tiles/block, LDS double-buffered.
// ---------------------------------------------------------------------------
__global__ __launch_bounds__(256, 2) void proj_fused(
    const float* __restrict__ tgt, const float* __restrict__ ref,
    const float* __restrict__ Wt, const float* __restrict__ Wr,
    const float* __restrict__ Wo, const float* __restrict__ bt,
    const float* __restrict__ br, const float* __restrict__ bo,
    unsigned short* __restrict__ Qw, unsigned short* __restrict__ Kw,
    unsigned short* __restrict__ Vw, float* __restrict__ Gw)
{
    __shared__ __align__(16) unsigned short Xs[2][64 * 128];   // 2 x 16KB
    const int t = threadIdx.x;
    const int sl2 = blockIdx.y >> 3;         // 0 = tgt (Q+G), 1 = ref (K+V)
    const int b = blockIdx.y & 7;
    const int tok0 = blockIdx.x << 7;        // 128 tokens per block (2 tiles)

    const int w = t >> 6, lane = t & 63;
    const int lg = (lane >> 4) & 3, lm = lane & 15;

    const float* X = sl2 ? ref : tgt;
    const float* Xb0 = X + ((size_t)b * kC) * kN + tok0;
    unsigned short* Vout = Vw + ((size_t)b * kC) * kN + tok0;

    const float* Wqk  = sl2 ? Wr : Wt;
    const float* bqk  = sl2 ? br : bt;
    const float scale = sl2 ? 1.0f : kLog2e;

    f16x8 wfq[4];
    float bq[4];
    {
        const int ocb = w * 16;
        #pragma unroll
        for (int ks = 0; ks < 4; ++ks) {
            const float* wp = Wqk + (size_t)(ocb + lm) * kC + ks * 32 + lg * 8;
            f32x4 f0 = *(const f32x4*)wp;
            f32x4 f1 = *(const f32x4*)(wp + 4);
            union { f16x8 h; uint4 u; } cv;
            cv.u = make_uint4(pkrtz(f0[0] * scale, f0[1] * scale),
                              pkrtz(f0[2] * scale, f0[3] * scale),
                              pkrtz(f1[0] * scale, f1[1] * scale),
                              pkrtz(f1[2] * scale, f1[3] * scale));
            wfq[ks] = cv.h;
        }
        #pragma unroll
        for (int r = 0; r < 4; ++r) bq[r] = bqk[ocb + lg * 4 + r] * scale;
    }

    f16x8 wfg[2][4];
    float bg[2][4];
    if (sl2 == 0) {
        const int ocb = w * 32;
        #pragma unroll
        for (int ot = 0; ot < 2; ++ot) {
            const int oc = ocb + ot * 16 + lm;
            #pragma unroll
            for (int ks = 0; ks < 4; ++ks) {
                const float* wp = Wo + (size_t)oc * kC + ks * 32 + lg * 8;
                f32x4 f0 = *(const f32x4*)wp;
                f32x4 f1 = *(const f32x4*)(wp + 4);
                union { f16x8 h; uint4 u; } cv;
                cv.u = make_uint4(pkrtz(f0[0], f0[1]), pkrtz(f0[2], f0[3]),
                                  pkrtz(f1[0], f1[1]), pkrtz(f1[2], f1[3]));
                wfg[ot][ks] = cv.h;
            }
            #pragma unroll
            for (int r = 0; r < 4; ++r) bg[ot][r] = bo[ocb + ot * 16 + lg * 4 + r];
        }
    }

    const int tk4 = (t & 15) * 4;
    const int c8  = (t >> 4) * 8;

    auto loadX = [&](int toff, f32x4* xv) {
        #pragma unroll
        for (int j = 0; j < 8; ++j)
            xv[j] = *(const f32x4*)(Xb0 + (size_t)(c8 + j) * kN + toff + tk4);
    };
    auto stageX = [&](const f32x4* xv, unsigned short* Xsb, int toff) {
        if (sl2 == 1) {
            #pragma unroll
            for (int j = 0; j < 8; ++j)
                *(uint2*)(Vout + (size_t)(c8 + j) * kN + toff + tk4) =
                    make_uint2(pkrtz(xv[j][0], xv[j][1]), pkrtz(xv[j][2], xv[j][3]));
        }
        #pragma unroll
        for (int s = 0; s < 4; ++s) {        // s STATIC (rule #20)
            const int tok = tk4 + s;
            const int cc = (c8 >> 3) ^ (tok & 7);
            uint4 pk;
            pk.x = pkrtz(xv[0][s], xv[1][s]);
            pk.y = pkrtz(xv[2][s], xv[3][s]);
            pk.z = pkrtz(xv[4][s], xv[5][s]);
            pk.w = pkrtz(xv[6][s], xv[7][s]);
            *(uint4*)(Xsb + tok * 128 + cc * 8) = pk;
        }
    };
    auto compute = [&](const unsigned short* Xsb, int tokb) {
        unsigned short* outp = (sl2 ? Kw : Qw) + ((size_t)b * kN + tokb) * kCH;
        float* Gb = Gw + ((size_t)b * kC) * kN + tokb;
        const int ocq = w * 16;
        const int ocg = w * 32;
        #pragma unroll
        for (int ns = 0; ns < 4; ++ns) {
            const int tok = ns * 16 + lm;
            f16x8 xf[4];
            #pragma unroll
            for (int ks = 0; ks < 4; ++ks)
                xf[ks] = *(const f16x8*)(Xsb + tok * 128 +
                                         (((ks * 4 + lg) ^ (tok & 7)) << 3));
            {
                f32x4 acc = {bq[0], bq[1], bq[2], bq[3]};
                #pragma unroll
                for (int ks = 0; ks < 4; ++ks)
                    acc = __builtin_amdgcn_mfma_f32_16x16x32_f16(wfq[ks], xf[ks], acc, 0, 0, 0);
                uint2 pk;
                pk.x = pkrtz(fmaxf(acc[0], 0.f), fmaxf(acc[1], 0.f));
                pk.y = pkrtz(fmaxf(acc[2], 0.f), fmaxf(acc[3], 0.f));
                *(uint2*)(outp + (size_t)tok * kCH + ocq + lg * 4) = pk;
            }
            if (sl2 == 0) {
                #pragma unroll
                for (int ot = 0; ot < 2; ++ot) {
                    f32x4 acc = {bg[ot][0], bg[ot][1], bg[ot][2], bg[ot][3]};
                    #pragma unroll
                    for (int ks = 0; ks < 4; ++ks)
                        acc = __builtin_amdgcn_mfma_f32_16x16x32_f16(wfg[ot][ks], xf[ks], acc, 0, 0, 0);
                    #pragma unroll
                    for (int r = 0; r < 4; ++r)
                        Gb[(size_t)(ocg + ot * 16 + lg * 4 + r) * kN + tok] = acc[r];
                }
            }
        }
    };

    f32x4 xv[8], xw[8];
    loadX(0, xv);
    stageX(xv, Xs[0], 0);
    __syncthreads();
    loadX(64, xw);
    compute(Xs[0], tok0);
    stageX(xw, Xs[1], 64);
    __syncthreads();
    compute(Xs[1], tok0 + 64);
}

// ---------------------------------------------------------------------------
// Flash attention R5: 32 q-rows/wave (2x16 halves), 128 q-rows/block.
// K/V LDS fragments are loaded ONCE per wave and feed BOTH q-halves,
// halving per-CU LDS-read traffic (the measured bottleneck: 68% of cycles).
// Grid 256 = 1 block/CU, 4 waves, 64KB LDS. Staging/swizzle/barrier
// structure identical to flash7.
// ---------------------------------------------------------------------------
__global__ __launch_bounds__(256, 1) void flash8_kernel(
    const unsigned short* __restrict__ Qw,   // [8][4096][64] fp16 (x log2e)
    const unsigned short* __restrict__ Kw,   // [8][4096][64] fp16
    const unsigned short* __restrict__ Vw,   // [8][128][4096] fp16
    const float* __restrict__ Gw,            // [8][128][4096] fp32 gate
    float* __restrict__ out)                 // [8][128][4096]
{
    __shared__ __align__(16) unsigned short Ks[2][64 * 64];    // 16KB
    __shared__ __align__(16) unsigned short Vs[2][128 * 64];   // 32KB
    __shared__ __align__(16) unsigned short Ps[128 * 64];      // 16KB

    const int t = threadIdx.x;
    const int b = blockIdx.x & 7;
    const int n0 = (blockIdx.x >> 3) << 7;   // 128 q-rows per block
    const int w = t >> 6, lane = t & 63;
    const int lg = (lane >> 4) & 3, lm = lane & 15;
    const int qw0 = w * 32;                  // wave's first q-row (local)
    const int swz = lm & 7;

    const unsigned short* Qb = Qw + ((size_t)b * kN) * kCH;
    const unsigned short* Kb = Kw + ((size_t)b * kN) * kCH;
    const unsigned short* Vb = Vw + ((size_t)b * kC) * kN;

    f16x8 qf[2][2];
    #pragma unroll
    for (int h = 0; h < 2; ++h) {
        const unsigned short* qp = Qb + (size_t)(n0 + qw0 + h * 16 + lm) * kCH;
        qf[h][0] = *(const f16x8*)(qp + (lg << 3));
        qf[h][1] = *(const f16x8*)(qp + 32 + (lg << 3));
    }

    const int srow = t >> 3, scol = t & 7;
    const int sco  = (scol ^ (srow & 7)) << 3;
    const int wv   = t >> 6;

    const int fswz0 = (lg ^ swz) << 3;
    const int fswz1 = ((4 | lg) ^ swz) << 3;
    int psw[2][4];
    #pragma unroll
    for (int h = 0; h < 2; ++h)
        #pragma unroll
        for (int mb = 0; mb < 4; ++mb)
            psw[h][mb] = (qw0 + h * 16 + lm) * 64 +
                         (((2 * mb + (lg >> 1)) ^ swz) << 3) + ((lg & 1) << 2);

    union { f16x8 h; uint4 u; } onec;
    onec.u = make_uint4(0x3c003c00u, 0x3c003c00u, 0x3c003c00u, 0x3c003c00u);
    const f16x8 onev = onec.h;               // all fp16 1.0

    f32x4 O[2][8];
    #pragma unroll
    for (int h = 0; h < 2; ++h)
        #pragma unroll
        for (int cb = 0; cb < 8; ++cb) O[h][cb] = (f32x4){0.f, 0.f, 0.f, 0.f};
    f32x4 L[2] = {(f32x4){0.f, 0.f, 0.f, 0.f}, (f32x4){0.f, 0.f, 0.f, 0.f}};
    float m_run[2] = {0.0f, 0.0f};           // S >= 0 (relu inputs)

    unsigned short* Ks0 = Ks[0]; unsigned short* Ks1 = Ks[1];
    unsigned short* Vs0 = Vs[0]; unsigned short* Vs1 = Vs[1];

    auto stage = [&](unsigned short* Kd, unsigned short* Vd, int m0) {
        g2l16(Kb + (size_t)(m0 + srow) * kCH + sco,      Kd + wv * 512);
        g2l16(Kb + (size_t)(m0 + 32 + srow) * kCH + sco, Kd + 2048 + wv * 512);
        #pragma unroll
        for (int j = 0; j < 4; ++j)
            g2l16(Vb + (size_t)(32 * j + srow) * kN + m0 + sco,
                  Vd + j * 2048 + wv * 512);
    };
    stage(Ks0, Vs0, 0);                      // prologue: tile 0 -> buffer 0

    auto tile = [&](const unsigned short* Kc, const unsigned short* Vc,
                    unsigned short* Kn, unsigned short* Vn, int kt) {
        __syncthreads();                     // staged tile ready (vmcnt drained)
        if (kt + 1 < kN / 64) stage(Kn, Vn, (kt + 1) << 6);

        // ---- QK^T -> S^T (log2 domain); K frags shared across q-halves ----
        f32x4 s[2][4];
        __builtin_amdgcn_s_setprio(1);
        #pragma unroll
        for (int mb = 0; mb < 4; ++mb) {
            const unsigned short* kr = Kc + ((mb * 16 + lm) << 6);
            f16x8 kf0 = *(const f16x8*)(kr + fswz0);
            f16x8 kf1 = *(const f16x8*)(kr + fswz1);
            #pragma unroll
            for (int h = 0; h < 2; ++h) {
                f32x4 acc = (f32x4){0.f, 0.f, 0.f, 0.f};
                acc = __builtin_amdgcn_mfma_f32_16x16x32_f16(kf0, qf[h][0], acc, 0, 0, 0);
                acc = __builtin_amdgcn_mfma_f32_16x16x32_f16(kf1, qf[h][1], acc, 0, 0, 0);
                s[h][mb] = acc;
            }
        }
        __builtin_amdgcn_s_setprio(0);

        // ---- online softmax (base 2), per half ----
        float mloc[2];
        #pragma unroll
        for (int h = 0; h < 2; ++h) {
            float m = 0.0f;
            #pragma unroll
            for (int mb = 0; mb < 4; ++mb)
                #pragma unroll
                for (int r = 0; r < 4; ++r) m = fmaxf(m, s[h][mb][r]);
            m = fmaxf(m, __shfl_xor(m, 16, 64));
            m = fmaxf(m, __shfl_xor(m, 32, 64));
            mloc[h] = m;
        }
        const bool upd = __any((mloc[0] > m_run[0]) | (mloc[1] > m_run[1]));
        float mnew[2];
        #pragma unroll
        for (int h = 0; h < 2; ++h)
            mnew[h] = upd ? fmaxf(m_run[h], mloc[h]) : m_run[h];

        #pragma unroll
        for (int h = 0; h < 2; ++h)
            #pragma unroll
            for (int mb = 0; mb < 4; ++mb) {
                unsigned plo = pkrtz(x2(s[h][mb][0] - mnew[h]), x2(s[h][mb][1] - mnew[h]));
                unsigned phi = pkrtz(x2(s[h][mb][2] - mnew[h]), x2(s[h][mb][3] - mnew[h]));
                *(uint2*)(Ps + psw[h][mb]) = make_uint2(plo, phi);
            }

        if (upd) {
            #pragma unroll
            for (int h = 0; h < 2; ++h) {
                float alpha = x2(m_run[h] - mnew[h]);
                float a0 = __shfl(alpha, (lg << 2) + 0, 64);
                float a1 = __shfl(alpha, (lg << 2) + 1, 64);
                float a2 = __shfl(alpha, (lg << 2) + 2, 64);
                float a3 = __shfl(alpha, (lg << 2) + 3, 64);
                #pragma unroll
                for (int cb = 0; cb < 8; ++cb) {
                    O[h][cb][0] *= a0; O[h][cb][1] *= a1;
                    O[h][cb][2] *= a2; O[h][cb][3] *= a3;
                }
                L[h][0] *= a0; L[h][1] *= a1; L[h][2] *= a2; L[h][3] *= a3;
                m_run[h] = mnew[h];
            }
        }

        // ---- PV + row-sum; V frags shared across q-halves ----
        f16x8 pf[2][2];
        #pragma unroll
        for (int h = 0; h < 2; ++h) {
            const unsigned short* pr = Ps + (qw0 + h * 16 + lm) * 64;
            pf[h][0] = *(const f16x8*)(pr + fswz0);
            pf[h][1] = *(const f16x8*)(pr + fswz1);
        }
        __builtin_amdgcn_s_setprio(1);
        #pragma unroll
        for (int h = 0; h < 2; ++h) {
            L[h] = __builtin_amdgcn_mfma_f32_16x16x32_f16(pf[h][0], onev, L[h], 0, 0, 0);
            L[h] = __builtin_amdgcn_mfma_f32_16x16x32_f16(pf[h][1], onev, L[h], 0, 0, 0);
        }
        #pragma unroll
        for (int cb = 0; cb < 8; ++cb) {
            const unsigned short* vr = Vc + ((cb * 16 + lm) << 6);
            f16x8 vf0 = *(const f16x8*)(vr + fswz0);
            f16x8 vf1 = *(const f16x8*)(vr + fswz1);
            #pragma unroll
            for (int h = 0; h < 2; ++h) {
                O[h][cb] = __builtin_amdgcn_mfma_f32_16x16x32_f16(pf[h][0], vf0, O[h][cb], 0, 0, 0);
                O[h][cb] = __builtin_amdgcn_mfma_f32_16x16x32_f16(pf[h][1], vf1, O[h][cb], 0, 0, 0);
            }
        }
        __builtin_amdgcn_s_setprio(0);
    };

    for (int kt = 0; kt < kN / 64; kt += 2) {
        tile(Ks0, Vs0, Ks1, Vs1, kt);        // even: compute buf0, stage buf1
        tile(Ks1, Vs1, Ks0, Vs0, kt + 1);    // odd : compute buf1, stage buf0
    }

    // ---- epilogue: normalize, gate, store float4 (per half) ----
    const float* Gb = Gw + ((size_t)b * kC) * kN;
    float* Ob = out + ((size_t)b * kC) * kN;
    #pragma unroll
    for (int h = 0; h < 2; ++h) {
        const float i0 = 1.0f / L[h][0], i1 = 1.0f / L[h][1];
        const float i2 = 1.0f / L[h][2], i3 = 1.0f / L[h][3];
        #pragma unroll
        for (int cb = 0; cb < 8; ++cb) {
            int c = cb * 16 + lm;
            size_t base = (size_t)c * kN + n0 + qw0 + h * 16 + (lg << 2);
            float4 g = *(const float4*)(Gb + base);
            float4 res;
            res.x = O[h][cb][0] * i0 * g.x;
            res.y = O[h][cb][1] * i1 * g.y;
            res.z = O[h][cb][2] * i2 * g.z;
            res.w = O[h][cb][3] * i3 * g.w;
            *(float4*)(Ob + base) = res;
        }
    }
}

// ---------------------------------------------------------------------------
extern "C" void kernel_launch(void* const* d_in, const int* in_sizes, int n_in,
                              void* d_out, int out_size, void* d_ws, size_t ws_size,
                              hipStream_t stream) {
    const float* tgt   = (const float*)d_in[0];
    const float* ref   = (const float*)d_in[1];
    const float* W_tgt = (const float*)d_in[2];
    const float* b_tgt = (const float*)d_in[3];
    const float* W_ref = (const float*)d_in[4];
    const float* b_ref = (const float*)d_in[5];
    const float* W_out = (const float*)d_in[6];
    const float* b_out = (const float*)d_in[7];
    float* out = (float*)d_out;

    const size_t QK = (size_t)8 * kN * kCH;              // fp16 -> 4 MB each
    const size_t CV = (size_t)8 * kC * kN;               // fp16 -> 8 MB
    unsigned short* Qw = (unsigned short*)d_ws;          // 4 MB
    unsigned short* Kw = Qw + QK;                        // 4 MB
    unsigned short* Vw = Kw + QK;                        // 8 MB
    float*          Gw = (float*)(Vw + CV);              // 16 MB (total 32 MB)

    proj_fused<<<dim3(32, 16), 256, 0, stream>>>(tgt, ref, W_tgt, W_ref, W_out,
                                                 b_tgt, b_ref, b_out, Qw, Kw, Vw, Gw);
    flash8_kernel<<<dim3(256), 256, 0, stream>>>(Qw, Kw, Vw, Gw, out);
}

// Round 6
// 195.274 us; speedup vs baseline: 1.0741x; 1.0741x over previous
//
#include <hip/hip_runtime.h>

typedef __attribute__((ext_vector_type(8))) _Float16 f16x8;   // 8 fp16 = 4 VGPRs
typedef __attribute__((ext_vector_type(4))) float f32x4;

constexpr int kC  = 128;
constexpr int kCH = 64;
constexpr int kN  = 4096;
constexpr float kLog2e = 1.4426950408889634f;

__device__ __forceinline__ unsigned pkrtz(float a, float b) {
    union { __fp16 __attribute__((ext_vector_type(2))) v; unsigned u; } cv;
    cv.v = __builtin_amdgcn_cvt_pkrtz(a, b);
    return cv.u;
}

__device__ __forceinline__ float x2(float x) {        // bare v_exp_f32
    return __builtin_amdgcn_exp2f(x);
}

// direct global->LDS DMA, 16B per lane, dest = wave-uniform base + lane*16
__device__ __forceinline__ void g2l16(const unsigned short* g, unsigned short* l) {
    __builtin_amdgcn_global_load_lds(
        (const __attribute__((address_space(1))) unsigned int*)(g),
        (__attribute__((address_space(3))) unsigned int*)(l),
        16, 0, 0);
}

// LDS-only barrier: does NOT drain vmcnt, so global_load_lds prefetch stays
// in flight across it (rule 18: sched_barrier after inline-asm waitcnt).
__device__ __forceinline__ void lds_barrier() {
    asm volatile("s_waitcnt lgkmcnt(0)" ::: "memory");
    __builtin_amdgcn_sched_barrier(0);
    __builtin_amdgcn_s_barrier();
}

// ---------------------------------------------------------------------------
// K/V projection only (R6): ref -> K = relu(Wr.ref+br) fp16 [b][n][64],
// V = fp16(ref) [b][128][n]. Q and G moved into the flash kernel.
// Grid (64, 8) = 512 blocks (2/CU), 256 thr, single 64-token tile, 16KB LDS.
// ---------------------------------------------------------------------------
__global__ __launch_bounds__(256, 2) void proj_kv(
    const float* __restrict__ ref, const float* __restrict__ Wr,
    const float* __restrict__ br, unsigned short* __restrict__ Kw,
    unsigned short* __restrict__ Vw)
{
    __shared__ __align__(16) unsigned short Xs[64 * 128];      // [tok][c] 16KB
    const int t = threadIdx.x;
    const int b = blockIdx.y;
    const int tokb = blockIdx.x << 6;        // 64 tokens / block

    const int w = t >> 6, lane = t & 63;
    const int lg = (lane >> 4) & 3, lm = lane & 15;

    const float* Xb = ref + ((size_t)b * kC) * kN + tokb;
    unsigned short* Vout = Vw + ((size_t)b * kC) * kN + tokb;

    // ---- issue X tile loads ----
    const int tk4 = (t & 15) * 4;
    const int c8  = (t >> 4) * 8;
    f32x4 xv[8];
    #pragma unroll
    for (int j = 0; j < 8; ++j)
        xv[j] = *(const f32x4*)(Xb + (size_t)(c8 + j) * kN + tk4);

    // ---- Wr fragments (overlap X-load latency) ----
    f16x8 wf[4];
    float bq[4];
    const int ocb = w * 16;
    #pragma unroll
    for (int ks = 0; ks < 4; ++ks) {
        const float* wp = Wr + (size_t)(ocb + lm) * kC + ks * 32 + lg * 8;
        f32x4 f0 = *(const f32x4*)wp;
        f32x4 f1 = *(const f32x4*)(wp + 4);
        union { f16x8 h; uint4 u; } cv;
        cv.u = make_uint4(pkrtz(f0[0], f0[1]), pkrtz(f0[2], f0[3]),
                          pkrtz(f1[0], f1[1]), pkrtz(f1[2], f1[3]));
        wf[ks] = cv.h;
    }
    #pragma unroll
    for (int r = 0; r < 4; ++r) bq[r] = br[ocb + lg * 4 + r];

    // ---- V passthrough + LDS stage (fp16 [tok][c], chunk cc ^= tok&7) ----
    #pragma unroll
    for (int j = 0; j < 8; ++j)
        *(uint2*)(Vout + (size_t)(c8 + j) * kN + tk4) =
            make_uint2(pkrtz(xv[j][0], xv[j][1]), pkrtz(xv[j][2], xv[j][3]));
    #pragma unroll
    for (int s = 0; s < 4; ++s) {            // s STATIC (rule #20)
        const int tok = tk4 + s;
        const int cc = (c8 >> 3) ^ (tok & 7);
        uint4 pk;
        pk.x = pkrtz(xv[0][s], xv[1][s]);
        pk.y = pkrtz(xv[2][s], xv[3][s]);
        pk.z = pkrtz(xv[4][s], xv[5][s]);
        pk.w = pkrtz(xv[6][s], xv[7][s]);
        *(uint4*)(Xs + tok * 128 + cc * 8) = pk;
    }
    __syncthreads();

    // ---- K: 64 oc, relu, fp16 [tok][oc] out ----
    unsigned short* outp = Kw + ((size_t)b * kN + tokb) * kCH;
    #pragma unroll
    for (int ns = 0; ns < 4; ++ns) {
        const int tok = ns * 16 + lm;
        f16x8 xf[4];
        #pragma unroll
        for (int ks = 0; ks < 4; ++ks)
            xf[ks] = *(const f16x8*)(Xs + tok * 128 +
                                     (((ks * 4 + lg) ^ (tok & 7)) << 3));
        f32x4 acc = {bq[0], bq[1], bq[2], bq[3]};
        #pragma unroll
        for (int ks = 0; ks < 4; ++ks)
            acc = __builtin_amdgcn_mfma_f32_16x16x32_f16(wf[ks], xf[ks], acc, 0, 0, 0);
        uint2 pk;
        pk.x = pkrtz(fmaxf(acc[0], 0.f), fmaxf(acc[1], 0.f));
        pk.y = pkrtz(fmaxf(acc[2], 0.f), fmaxf(acc[3], 0.f));
        *(uint2*)(outp + (size_t)tok * kCH + ocb + lg * 4) = pk;
    }
}

// ---------------------------------------------------------------------------
// Flash attention R6: flash7's validated main loop (byte-identical), plus
//   prologue: Q = relu(Wt.tgt+bt)*log2e computed in-kernel (tgt tile staged
//     into dead Vs[1]; Q packed through Ps with the psw/fswz involution;
//     lgkm-only barriers keep the tile-0 K/V DMA in flight)
//   epilogue: G = Wo.tgt+bo computed in-kernel (tgt re-staged into dead
//     Vs[0]; G^T D-layout matches O exactly), gate applied in registers.
// Removes the Qw/Gw HBM round-trips entirely.
// ---------------------------------------------------------------------------
__global__ __launch_bounds__(256, 2) void flash9_kernel(
    const float* __restrict__ tgt,           // [8][128][4096] fp32
    const unsigned short* __restrict__ Kw,   // [8][4096][64] fp16
    const unsigned short* __restrict__ Vw,   // [8][128][4096] fp16
    const float* __restrict__ Wt, const float* __restrict__ bt,
    const float* __restrict__ Wo, const float* __restrict__ bo,
    float* __restrict__ out)                 // [8][128][4096]
{
    __shared__ __align__(16) unsigned short Ks[2][64 * 64];    // 16KB
    __shared__ __align__(16) unsigned short Vs[2][128 * 64];   // 32KB
    __shared__ __align__(16) unsigned short Ps[64 * 64];       // 8KB

    const int t = threadIdx.x;
    const int b = blockIdx.x & 7;
    const int n0 = (blockIdx.x >> 3) << 6;
    const int w = t >> 6, lane = t & 63;
    const int lg = (lane >> 4) & 3, lm = lane & 15;
    const int row_q = w * 16 + lm;
    const int swz = lm & 7;

    const unsigned short* Kb = Kw + ((size_t)b * kN) * kCH;
    const unsigned short* Vb = Vw + ((size_t)b * kC) * kN;
    const float* Tb = tgt + ((size_t)b * kC) * kN + n0;

    const int srow = t >> 3, scol = t & 7;
    const int sco  = (scol ^ (srow & 7)) << 3;
    const int wv   = t >> 6;

    const int fswz0 = (lg ^ swz) << 3;
    const int fswz1 = ((4 | lg) ^ swz) << 3;
    int psw[4];
    #pragma unroll
    for (int mb = 0; mb < 4; ++mb)
        psw[mb] = row_q * 64 + (((2 * mb + (lg >> 1)) ^ swz) << 3) + ((lg & 1) << 2);

    union { f16x8 h; uint4 u; } onec;
    onec.u = make_uint4(0x3c003c00u, 0x3c003c00u, 0x3c003c00u, 0x3c003c00u);
    const f16x8 onev = onec.h;               // all fp16 1.0

    f32x4 O[8];
    #pragma unroll
    for (int cb = 0; cb < 8; ++cb) O[cb] = (f32x4){0.f, 0.f, 0.f, 0.f};
    f32x4 L = (f32x4){0.f, 0.f, 0.f, 0.f};
    float m_run = 0.0f;

    unsigned short* Ks0 = Ks[0]; unsigned short* Ks1 = Ks[1];
    unsigned short* Vs0 = Vs[0]; unsigned short* Vs1 = Vs[1];

    auto stage = [&](unsigned short* Kd, unsigned short* Vd, int m0) {
        g2l16(Kb + (size_t)(m0 + srow) * kCH + sco,      Kd + wv * 512);
        g2l16(Kb + (size_t)(m0 + 32 + srow) * kCH + sco, Kd + 2048 + wv * 512);
        #pragma unroll
        for (int j = 0; j < 4; ++j)
            g2l16(Vb + (size_t)(32 * j + srow) * kN + m0 + sco,
                  Vd + j * 2048 + wv * 512);
    };
    stage(Ks0, Vs0, 0);                      // tile-0 DMA in flight

    const int tk4 = (t & 15) * 4;            // token within 64-tile
    const int c8  = (t >> 4) * 8;            // channel group

    auto stageT = [&](unsigned short* Xs) {  // tgt fp32 -> fp16 LDS [tok][128c]
        f32x4 xv[8];
        #pragma unroll
        for (int j = 0; j < 8; ++j)
            xv[j] = *(const f32x4*)(Tb + (size_t)(c8 + j) * kN + tk4);
        #pragma unroll
        for (int s = 0; s < 4; ++s) {        // s STATIC (rule #20)
            const int tok = tk4 + s;
            const int cc = (c8 >> 3) ^ (tok & 7);
            uint4 pk;
            pk.x = pkrtz(xv[0][s], xv[1][s]);
            pk.y = pkrtz(xv[2][s], xv[3][s]);
            pk.z = pkrtz(xv[4][s], xv[5][s]);
            pk.w = pkrtz(xv[6][s], xv[7][s]);
            *(uint4*)(Xs + tok * 128 + cc * 8) = pk;
        }
    };

    // ---- prologue: Q in-kernel (tgt tile in Vs1, Q packed through Ps) ----
    f16x8 qf0, qf1;
    {
        f16x8 wq[4];
        float bq4[4];
        #pragma unroll
        for (int ks = 0; ks < 4; ++ks) {
            const float* wp = Wt + (size_t)(w * 16 + lm) * kC + ks * 32 + lg * 8;
            f32x4 f0 = *(const f32x4*)wp;
            f32x4 f1 = *(const f32x4*)(wp + 4);
            union { f16x8 h; uint4 u; } cv;
            cv.u = make_uint4(pkrtz(f0[0] * kLog2e, f0[1] * kLog2e),
                              pkrtz(f0[2] * kLog2e, f0[3] * kLog2e),
                              pkrtz(f1[0] * kLog2e, f1[1] * kLog2e),
                              pkrtz(f1[2] * kLog2e, f1[3] * kLog2e));
            wq[ks] = cv.h;
        }
        #pragma unroll
        for (int r = 0; r < 4; ++r) bq4[r] = bt[w * 16 + lg * 4 + r] * kLog2e;

        stageT(Vs1);
        lds_barrier();                       // tgt tile visible; DMA stays in flight

        // wave w computes oc-tile w*16..w*16+16 for all 64 tokens
        const int qsw = lm * 64 + (((2 * w + (lg >> 1)) ^ (lm & 7)) << 3) + ((lg & 1) << 2);
        #pragma unroll
        for (int ns = 0; ns < 4; ++ns) {
            const int tok = ns * 16 + lm;
            f16x8 xf[4];
            #pragma unroll
            for (int ks = 0; ks < 4; ++ks)
                xf[ks] = *(const f16x8*)(Vs1 + tok * 128 +
                                         (((ks * 4 + lg) ^ (tok & 7)) << 3));
            f32x4 acc = {bq4[0], bq4[1], bq4[2], bq4[3]};
            #pragma unroll
            for (int ks = 0; ks < 4; ++ks)
                acc = __builtin_amdgcn_mfma_f32_16x16x32_f16(wq[ks], xf[ks], acc, 0, 0, 0);
            *(uint2*)(Ps + qsw + ns * 1024) = make_uint2(
                pkrtz(fmaxf(acc[0], 0.f), fmaxf(acc[1], 0.f)),
                pkrtz(fmaxf(acc[2], 0.f), fmaxf(acc[3], 0.f)));
        }
        lds_barrier();                       // Q visible cross-wave
        qf0 = *(const f16x8*)(Ps + row_q * 64 + fswz0);
        qf1 = *(const f16x8*)(Ps + row_q * 64 + fswz1);
    }

    auto tile = [&](const unsigned short* Kc, const unsigned short* Vc,
                    unsigned short* Kn, unsigned short* Vn, int kt) {
        __syncthreads();                     // staged tile ready (vmcnt drained)
        if (kt + 1 < kN / 64) stage(Kn, Vn, (kt + 1) << 6);

        // ---- QK^T -> S^T (log2 domain) ----
        f32x4 s[4];
        __builtin_amdgcn_s_setprio(1);
        #pragma unroll
        for (int mb = 0; mb < 4; ++mb) {
            const unsigned short* kr = Kc + ((mb * 16 + lm) << 6);
            f16x8 kf0 = *(const f16x8*)(kr + fswz0);
            f16x8 kf1 = *(const f16x8*)(kr + fswz1);
            f32x4 acc = (f32x4){0.f, 0.f, 0.f, 0.f};
            acc = __builtin_amdgcn_mfma_f32_16x16x32_f16(kf0, qf0, acc, 0, 0, 0);
            acc = __builtin_amdgcn_mfma_f32_16x16x32_f16(kf1, qf1, acc, 0, 0, 0);
            s[mb] = acc;
        }
        __builtin_amdgcn_s_setprio(0);

        // ---- online softmax (base 2) ----
        float mloc = 0.0f;
        #pragma unroll
        for (int mb = 0; mb < 4; ++mb)
            #pragma unroll
            for (int r = 0; r < 4; ++r) mloc = fmaxf(mloc, s[mb][r]);
        mloc = fmaxf(mloc, __shfl_xor(mloc, 16, 64));
        mloc = fmaxf(mloc, __shfl_xor(mloc, 32, 64));
        const bool upd = __any(mloc > m_run);
        const float mnew = upd ? fmaxf(m_run, mloc) : m_run;

        #pragma unroll
        for (int mb = 0; mb < 4; ++mb) {
            unsigned plo = pkrtz(x2(s[mb][0] - mnew), x2(s[mb][1] - mnew));
            unsigned phi = pkrtz(x2(s[mb][2] - mnew), x2(s[mb][3] - mnew));
            *(uint2*)(Ps + psw[mb]) = make_uint2(plo, phi);
        }

        if (upd) {
            float alpha = x2(m_run - mnew);
            float a0 = __shfl(alpha, (lg << 2) + 0, 64);
            float a1 = __shfl(alpha, (lg << 2) + 1, 64);
            float a2 = __shfl(alpha, (lg << 2) + 2, 64);
            float a3 = __shfl(alpha, (lg << 2) + 3, 64);
            #pragma unroll
            for (int cb = 0; cb < 8; ++cb) {
                O[cb][0] *= a0; O[cb][1] *= a1; O[cb][2] *= a2; O[cb][3] *= a3;
            }
            L[0] *= a0; L[1] *= a1; L[2] *= a2; L[3] *= a3;
            m_run = mnew;
        }

        // ---- PV + row-sum (ones MFMA) ----
        f16x8 pf0 = *(const f16x8*)(Ps + row_q * 64 + fswz0);
        f16x8 pf1 = *(const f16x8*)(Ps + row_q * 64 + fswz1);
        __builtin_amdgcn_s_setprio(1);
        L = __builtin_amdgcn_mfma_f32_16x16x32_f16(pf0, onev, L, 0, 0, 0);
        L = __builtin_amdgcn_mfma_f32_16x16x32_f16(pf1, onev, L, 0, 0, 0);
        #pragma unroll
        for (int cb = 0; cb < 8; ++cb) {
            const unsigned short* vr = Vc + ((cb * 16 + lm) << 6);
            f16x8 vf0 = *(const f16x8*)(vr + fswz0);
            f16x8 vf1 = *(const f16x8*)(vr + fswz1);
            O[cb] = __builtin_amdgcn_mfma_f32_16x16x32_f16(pf0, vf0, O[cb], 0, 0, 0);
            O[cb] = __builtin_amdgcn_mfma_f32_16x16x32_f16(pf1, vf1, O[cb], 0, 0, 0);
        }
        __builtin_amdgcn_s_setprio(0);
    };

    for (int kt = 0; kt < kN / 64; kt += 2) {
        tile(Ks0, Vs0, Ks1, Vs1, kt);        // even: compute buf0, stage buf1
        tile(Ks1, Vs1, Ks0, Vs0, kt + 1);    // odd : compute buf1, stage buf0
    }

    // ---- epilogue: G in-kernel, normalize, gate, store float4 ----
    __syncthreads();                         // all waves done with Vs0
    stageT(Vs0);                             // tgt tile (L3-resident re-read)
    __syncthreads();

    const float i0 = 1.0f / L[0], i1 = 1.0f / L[1];
    const float i2 = 1.0f / L[2], i3 = 1.0f / L[3];
    float* Ob = out + ((size_t)b * kC) * kN;

    f16x8 tf[4];                             // A-operand: wave's 16 tokens
    #pragma unroll
    for (int ks = 0; ks < 4; ++ks)
        tf[ks] = *(const f16x8*)(Vs0 + row_q * 128 + (((ks * 4 + lg) ^ swz) << 3));

    #pragma unroll
    for (int cb = 0; cb < 8; ++cb) {
        const int c = cb * 16 + lm;
        f16x8 wo[4];                         // B-operand: Wo rows = oc cols
        #pragma unroll
        for (int ks = 0; ks < 4; ++ks) {
            const float* wp = Wo + (size_t)c * kC + ks * 32 + lg * 8;
            f32x4 f0 = *(const f32x4*)wp;
            f32x4 f1 = *(const f32x4*)(wp + 4);
            union { f16x8 h; uint4 u; } cv;
            cv.u = make_uint4(pkrtz(f0[0], f0[1]), pkrtz(f0[2], f0[3]),
                              pkrtz(f1[0], f1[1]), pkrtz(f1[2], f1[3]));
            wo[ks] = cv.h;
        }
        const float bc = bo[c];
        f32x4 g = {bc, bc, bc, bc};          // G^T tile: col=lm=c, row=token
        #pragma unroll
        for (int ks = 0; ks < 4; ++ks)
            g = __builtin_amdgcn_mfma_f32_16x16x32_f16(tf[ks], wo[ks], g, 0, 0, 0);

        size_t base = (size_t)c * kN + n0 + w * 16 + (lg << 2);
        float4 res;
        res.x = O[cb][0] * i0 * g[0];
        res.y = O[cb][1] * i1 * g[1];
        res.z = O[cb][2] * i2 * g[2];
        res.w = O[cb][3] * i3 * g[3];
        *(float4*)(Ob + base) = res;
    }
}

// ---------------------------------------------------------------------------
extern "C" void kernel_launch(void* const* d_in, const int* in_sizes, int n_in,
                              void* d_out, int out_size, void* d_ws, size_t ws_size,
                              hipStream_t stream) {
    const float* tgt   = (const float*)d_in[0];
    const float* ref   = (const float*)d_in[1];
    const float* W_tgt = (const float*)d_in[2];
    const float* b_tgt = (const float*)d_in[3];
    const float* W_ref = (const float*)d_in[4];
    const float* b_ref = (const float*)d_in[5];
    const float* W_out = (const float*)d_in[6];
    const float* b_out = (const float*)d_in[7];
    float* out = (float*)d_out;

    const size_t QK = (size_t)8 * kN * kCH;              // fp16 -> 4 MB
    unsigned short* Kw = (unsigned short*)d_ws;          // 4 MB
    unsigned short* Vw = Kw + QK;                        // 8 MB (total 12 MB)

    proj_kv<<<dim3(64, 8), 256, 0, stream>>>(ref, W_ref, b_ref, Kw, Vw);
    flash9_kernel<<<dim3(512), 256, 0, stream>>>(tgt, Kw, Vw, W_tgt, b_tgt,
                                                 W_out, b_out, out);
}

// Round 7
// 186.457 us; speedup vs baseline: 1.1249x; 1.0473x over previous
//
#include <hip/hip_runtime.h>

typedef __attribute__((ext_vector_type(8))) _Float16 f16x8;   // 8 fp16 = 4 VGPRs
typedef __attribute__((ext_vector_type(4))) float f32x4;
typedef __attribute__((ext_vector_type(16))) float f32x16;

constexpr int kC  = 128;
constexpr int kCH = 64;
constexpr int kN  = 4096;
constexpr float kLog2e = 1.4426950408889634f;

__device__ __forceinline__ unsigned pkrtz(float a, float b) {
    union { __fp16 __attribute__((ext_vector_type(2))) v; unsigned u; } cv;
    cv.v = __builtin_amdgcn_cvt_pkrtz(a, b);
    return cv.u;
}

__device__ __forceinline__ float x2(float x) {        // bare v_exp_f32
    return __builtin_amdgcn_exp2f(x);
}

__device__ __forceinline__ float hadd2(unsigned u) {  // fp16 pair -> f32 sum
    union { unsigned v; _Float16 h[2]; } c; c.v = u;
    return (float)c.h[0] + (float)c.h[1];
}

// direct global->LDS DMA, 16B per lane, dest = wave-uniform base + lane*16
__device__ __forceinline__ void g2l16(const unsigned short* g, unsigned short* l) {
    __builtin_amdgcn_global_load_lds(
        (const __attribute__((address_space(1))) unsigned int*)(g),
        (__attribute__((address_space(3))) unsigned int*)(l),
        16, 0, 0);
}

// ---------------------------------------------------------------------------
// Fused projection — byte-identical to R4 (validated anchor). Two slices:
//   0: tgt -> Q,G   1: ref -> K,V. 2 token-tiles/block, LDS double-buffered.
// ---------------------------------------------------------------------------
__global__ __launch_bounds__(256, 2) void proj_fused(
    const float* __restrict__ tgt, const float* __restrict__ ref,
    const float* __restrict__ Wt, const float* __restrict__ Wr,
    const float* __restrict__ Wo, const float* __restrict__ bt,
    const float* __restrict__ br, const float* __restrict__ bo,
    unsigned short* __restrict__ Qw, unsigned short* __restrict__ Kw,
    unsigned short* __restrict__ Vw, float* __restrict__ Gw)
{
    __shared__ __align__(16) unsigned short Xs[2][64 * 128];   // 2 x 16KB
    const int t = threadIdx.x;
    const int sl2 = blockIdx.y >> 3;         // 0 = tgt (Q+G), 1 = ref (K+V)
    const int b = blockIdx.y & 7;
    const int tok0 = blockIdx.x << 7;        // 128 tokens per block (2 tiles)

    const int w = t >> 6, lane = t & 63;
    const int lg = (lane >> 4) & 3, lm = lane & 15;

    const float* X = sl2 ? ref : tgt;
    const float* Xb0 = X + ((size_t)b * kC) * kN + tok0;
    unsigned short* Vout = Vw + ((size_t)b * kC) * kN + tok0;

    const float* Wqk  = sl2 ? Wr : Wt;
    const float* bqk  = sl2 ? br : bt;
    const float scale = sl2 ? 1.0f : kLog2e;

    f16x8 wfq[4];
    float bq[4];
    {
        const int ocb = w * 16;
        #pragma unroll
        for (int ks = 0; ks < 4; ++ks) {
            const float* wp = Wqk + (size_t)(ocb + lm) * kC + ks * 32 + lg * 8;
            f32x4 f0 = *(const f32x4*)wp;
            f32x4 f1 = *(const f32x4*)(wp + 4);
            union { f16x8 h; uint4 u; } cv;
            cv.u = make_uint4(pkrtz(f0[0] * scale, f0[1] * scale),
                              pkrtz(f0[2] * scale, f0[3] * scale),
                              pkrtz(f1[0] * scale, f1[1] * scale),
                              pkrtz(f1[2] * scale, f1[3] * scale));
            wfq[ks] = cv.h;
        }
        #pragma unroll
        for (int r = 0; r < 4; ++r) bq[r] = bqk[ocb + lg * 4 + r] * scale;
    }

    f16x8 wfg[2][4];
    float bg[2][4];
    if (sl2 == 0) {
        const int ocb = w * 32;
        #pragma unroll
        for (int ot = 0; ot < 2; ++ot) {
            const int oc = ocb + ot * 16 + lm;
            #pragma unroll
            for (int ks = 0; ks < 4; ++ks) {
                const float* wp = Wo + (size_t)oc * kC + ks * 32 + lg * 8;
                f32x4 f0 = *(const f32x4*)wp;
                f32x4 f1 = *(const f32x4*)(wp + 4);
                union { f16x8 h; uint4 u; } cv;
                cv.u = make_uint4(pkrtz(f0[0], f0[1]), pkrtz(f0[2], f0[3]),
                                  pkrtz(f1[0], f1[1]), pkrtz(f1[2], f1[3]));
                wfg[ot][ks] = cv.h;
            }
            #pragma unroll
            for (int r = 0; r < 4; ++r) bg[ot][r] = bo[ocb + ot * 16 + lg * 4 + r];
        }
    }

    const int tk4 = (t & 15) * 4;
    const int c8  = (t >> 4) * 8;

    auto loadX = [&](int toff, f32x4* xv) {
        #pragma unroll
        for (int j = 0; j < 8; ++j)
            xv[j] = *(const f32x4*)(Xb0 + (size_t)(c8 + j) * kN + toff + tk4);
    };
    auto stageX = [&](const f32x4* xv, unsigned short* Xsb, int toff) {
        if (sl2 == 1) {
            #pragma unroll
            for (int j = 0; j < 8; ++j)
                *(uint2*)(Vout + (size_t)(c8 + j) * kN + toff + tk4) =
                    make_uint2(pkrtz(xv[j][0], xv[j][1]), pkrtz(xv[j][2], xv[j][3]));
        }
        #pragma unroll
        for (int s = 0; s < 4; ++s) {        // s STATIC (rule #20)
            const int tok = tk4 + s;
            const int cc = (c8 >> 3) ^ (tok & 7);
            uint4 pk;
            pk.x = pkrtz(xv[0][s], xv[1][s]);
            pk.y = pkrtz(xv[2][s], xv[3][s]);
            pk.z = pkrtz(xv[4][s], xv[5][s]);
            pk.w = pkrtz(xv[6][s], xv[7][s]);
            *(uint4*)(Xsb + tok * 128 + cc * 8) = pk;
        }
    };
    auto compute = [&](const unsigned short* Xsb, int tokb) {
        unsigned short* outp = (sl2 ? Kw : Qw) + ((size_t)b * kN + tokb) * kCH;
        float* Gb = Gw + ((size_t)b * kC) * kN + tokb;
        const int ocq = w * 16;
        const int ocg = w * 32;
        #pragma unroll
        for (int ns = 0; ns < 4; ++ns) {
            const int tok = ns * 16 + lm;
            f16x8 xf[4];
            #pragma unroll
            for (int ks = 0; ks < 4; ++ks)
                xf[ks] = *(const f16x8*)(Xsb + tok * 128 +
                                         (((ks * 4 + lg) ^ (tok & 7)) << 3));
            {
                f32x4 acc = {bq[0], bq[1], bq[2], bq[3]};
                #pragma unroll
                for (int ks = 0; ks < 4; ++ks)
                    acc = __builtin_amdgcn_mfma_f32_16x16x32_f16(wfq[ks], xf[ks], acc, 0, 0, 0);
                uint2 pk;
                pk.x = pkrtz(fmaxf(acc[0], 0.f), fmaxf(acc[1], 0.f));
                pk.y = pkrtz(fmaxf(acc[2], 0.f), fmaxf(acc[3], 0.f));
                *(uint2*)(outp + (size_t)tok * kCH + ocq + lg * 4) = pk;
            }
            if (sl2 == 0) {
                #pragma unroll
                for (int ot = 0; ot < 2; ++ot) {
                    f32x4 acc = {bg[ot][0], bg[ot][1], bg[ot][2], bg[ot][3]};
                    #pragma unroll
                    for (int ks = 0; ks < 4; ++ks)
                        acc = __builtin_amdgcn_mfma_f32_16x16x32_f16(wfg[ot][ks], xf[ks], acc, 0, 0, 0);
                    #pragma unroll
                    for (int r = 0; r < 4; ++r)
                        Gb[(size_t)(ocg + ot * 16 + lg * 4 + r) * kN + tok] = acc[r];
                }
            }
        }
    };

    f32x4 xv[8], xw[8];
    loadX(0, xv);
    stageX(xv, Xs[0], 0);
    __syncthreads();
    loadX(64, xw);
    compute(Xs[0], tok0);
    stageX(xw, Xs[1], 64);
    __syncthreads();
    compute(Xs[1], tok0 + 64);
}

// ---------------------------------------------------------------------------
// Flash attention R7: 32x32x16 MFMA + split-K wave pairs.
//   - Block = 64 q-rows, 4 waves: pair (qg) owns 32 q-rows; within a pair,
//     each wave (kh) takes half the keys of every tile (online softmax per
//     wave, one merge at the end).
//   - 32x32 D-layout (col=lane&31=q) makes softmax per-lane: no broadcast
//     shuffles; max/sum need one shfl_xor(32) each.
//   - P relaid to the PV B-operand IN-REGISTER (cvt_pk + shfl_xor(32) +
//     cndmask) -> Ps LDS buffer deleted (56->48KB), LDS reads/tile/wave
//     drop 28 -> 12 b128.
//   - Batch-major block remap: co-XCD blocks share K/V panels in L2.
// Fragment layouts: C/D = verified m74/m101 formula (col=lane&31,
// row=(reg&3)+8*(reg>>2)+4*(lane>>5)); A/B generalize the validated
// 16x16x32 pattern: row/col = lane&31, k = (lane>>5)*8 + j.
// ---------------------------------------------------------------------------
__global__ __launch_bounds__(256, 2) void flash10_kernel(
    const unsigned short* __restrict__ Qw,   // [8][4096][64] fp16 (x log2e)
    const unsigned short* __restrict__ Kw,   // [8][4096][64] fp16
    const unsigned short* __restrict__ Vw,   // [8][128][4096] fp16
    const float* __restrict__ Gw,            // [8][128][4096] fp32 gate
    float* __restrict__ out)                 // [8][128][4096]
{
    __shared__ __align__(16) unsigned short Ks[2][64 * 64];    // 16KB
    __shared__ __align__(16) unsigned short Vs[2][128 * 64];   // 32KB
    __shared__ float2 mlb[4][32];                              // 1KB merge buf

    const int t = threadIdx.x;
    const int b  = blockIdx.x >> 6;          // batch-major
    const int n0 = (blockIdx.x & 63) << 6;
    const int w = t >> 6, lane = t & 63;
    const int qg = w >> 1, kh = w & 1;       // q-group, key-half
    const int lq = lane & 31, hh = lane >> 5;
    const int n0q = n0 + qg * 32 + lq;       // this lane's q (global token)

    const unsigned short* Qb = Qw + ((size_t)b * kN + n0q) * kCH;
    const unsigned short* Kb = Kw + ((size_t)b * kN) * kCH;
    const unsigned short* Vb = Vw + ((size_t)b * kC) * kN;

    // Q B-frags: col=q (lane-resident), k(d) = st*16 + hh*8 + j
    f16x8 qf[4];
    #pragma unroll
    for (int st = 0; st < 4; ++st)
        qf[st] = *(const f16x8*)(Qb + st * 16 + hh * 8);

    // staging geometry (identical to flash7): linear LDS dest, XOR'd source
    const int srow = t >> 3, scol = t & 7;
    const int sco  = (scol ^ (srow & 7)) << 3;
    const int wv   = t >> 6;

    // fragment read addresses (swizzle involution matches staging)
    int ka[4];
    #pragma unroll
    for (int st = 0; st < 4; ++st)
        ka[st] = (kh * 32 + lq) * 64 + (((2 * st + hh) ^ (lq & 7)) << 3);
    int va[4][2];
    #pragma unroll
    for (int cb = 0; cb < 4; ++cb)
        #pragma unroll
        for (int s = 0; s < 2; ++s)
            va[cb][s] = (cb * 32 + lq) * 64 + (((kh * 4 + 2 * s + hh) ^ (lq & 7)) << 3);

    f32x16 O[4];
    #pragma unroll
    for (int cb = 0; cb < 4; ++cb)
        #pragma unroll
        for (int r = 0; r < 16; ++r) O[cb][r] = 0.f;
    float L = 0.f, m_run = 0.f;              // S >= 0 (relu inputs), exp2 domain

    unsigned short* Ks0 = Ks[0]; unsigned short* Ks1 = Ks[1];
    unsigned short* Vs0 = Vs[0]; unsigned short* Vs1 = Vs[1];

    auto stage = [&](unsigned short* Kd, unsigned short* Vd, int m0) {
        g2l16(Kb + (size_t)(m0 + srow) * kCH + sco,      Kd + wv * 512);
        g2l16(Kb + (size_t)(m0 + 32 + srow) * kCH + sco, Kd + 2048 + wv * 512);
        #pragma unroll
        for (int j = 0; j < 4; ++j)
            g2l16(Vb + (size_t)(32 * j + srow) * kN + m0 + sco,
                  Vd + j * 2048 + wv * 512);
    };
    stage(Ks0, Vs0, 0);                      // prologue: tile 0 -> buffer 0

    auto tile = [&](const unsigned short* Kc, const unsigned short* Vc,
                    unsigned short* Kn, unsigned short* Vn, int kt) {
        __syncthreads();                     // staged tile ready (vmcnt drained)
        if (kt + 1 < kN / 64) stage(Kn, Vn, (kt + 1) << 6);

        // ---- QK^T: S (32 keys x 32 q), keys = this wave's half ----
        f32x16 sa;
        #pragma unroll
        for (int r = 0; r < 16; ++r) sa[r] = 0.f;
        __builtin_amdgcn_s_setprio(1);
        #pragma unroll
        for (int st = 0; st < 4; ++st) {
            f16x8 kf = *(const f16x8*)(Kc + ka[st]);
            sa = __builtin_amdgcn_mfma_f32_32x32x16_f16(kf, qf[st], sa, 0, 0, 0);
        }
        __builtin_amdgcn_s_setprio(0);

        // ---- per-lane online softmax (lane owns one q-column) ----
        float mh = sa[0];
        #pragma unroll
        for (int r = 1; r < 16; ++r) mh = fmaxf(mh, sa[r]);
        float mq = fmaxf(mh, __shfl_xor(mh, 32));
        const bool upd = __any(mq > m_run);
        const float mnew = upd ? fmaxf(m_run, mq) : m_run;

        #pragma unroll
        for (int r = 0; r < 16; ++r) sa[r] = x2(sa[r] - mnew);
        unsigned P[8];
        #pragma unroll
        for (int i = 0; i < 8; ++i) P[i] = pkrtz(sa[2 * i], sa[2 * i + 1]);

        float ps = 0.f;                      // rowsum of fp16-ROUNDED P
        #pragma unroll
        for (int i = 0; i < 8; ++i) ps += hadd2(P[i]);
        ps += __shfl_xor(ps, 32);

        if (upd) {
            const float al = x2(m_run - mnew);
            #pragma unroll
            for (int cb = 0; cb < 4; ++cb) O[cb] *= al;
            L = L * al + ps;
            m_run = mnew;
        } else {
            L += ps;
        }

        // ---- in-register P relayout to B-frags (keys 16s..16s+15) ----
        f16x8 pf[2];
        #pragma unroll
        for (int s = 0; s < 2; ++s) {
            unsigned xa = __shfl_xor(P[4 * s + 0], 32);
            unsigned xb = __shfl_xor(P[4 * s + 1], 32);
            unsigned xc = __shfl_xor(P[4 * s + 2], 32);
            unsigned xd = __shfl_xor(P[4 * s + 3], 32);
            uint4 fu;
            fu.x = hh ? xc : P[4 * s + 0];
            fu.y = hh ? xd : P[4 * s + 1];
            fu.z = hh ? P[4 * s + 2] : xa;
            fu.w = hh ? P[4 * s + 3] : xb;
            union { uint4 u; f16x8 h; } cv; cv.u = fu;
            pf[s] = cv.h;
        }

        // ---- PV: O[cb] += V(32c x 16k) . P(16k x 32q) ----
        __builtin_amdgcn_s_setprio(1);
        #pragma unroll
        for (int cb = 0; cb < 4; ++cb) {
            #pragma unroll
            for (int s = 0; s < 2; ++s) {
                f16x8 vf = *(const f16x8*)(Vc + va[cb][s]);
                O[cb] = __builtin_amdgcn_mfma_f32_32x32x16_f16(vf, pf[s], O[cb], 0, 0, 0);
            }
        }
        __builtin_amdgcn_s_setprio(0);
    };

    for (int kt = 0; kt < kN / 64; kt += 2) {
        tile(Ks0, Vs0, Ks1, Vs1, kt);        // even: compute buf0, stage buf1
        tile(Ks1, Vs1, Ks0, Vs0, kt + 1);    // odd : compute buf1, stage buf0
    }

    // ---- epilogue: split-K merge across the wave pair, gate, store ----
    __syncthreads();
    mlb[w][lq] = make_float2(m_run, L);      // lanes lq and lq+32 write same val
    __syncthreads();
    const float2 pml = mlb[w ^ 1][lq];
    const float mt = fmaxf(m_run, pml.x);
    const float a  = x2(m_run - mt);
    const float Lt = L * a + pml.y * x2(pml.x - mt);

    float* Obuf = (float*)Vs;                // overlay dead V buffers (32KB)
    const int obase = qg * 4096 + lane * 64; // +rotation below: conflict-free
    #pragma unroll
    for (int cb = 0; cb < 4; ++cb) O[cb] *= a;

    if (kh) {                                // odd wave: publish scaled O
        #pragma unroll
        for (int c = 0; c < 16; ++c) {
            const int cb = c >> 2, q4 = c & 3;
            *(float4*)(Obuf + obase + (((c + lane) & 15) << 2)) =
                make_float4(O[cb][q4 * 4 + 0], O[cb][q4 * 4 + 1],
                            O[cb][q4 * 4 + 2], O[cb][q4 * 4 + 3]);
        }
    }
    __syncthreads();
    if (!kh) {                               // even wave: merge + gate + store
        #pragma unroll
        for (int c = 0; c < 16; ++c) {
            const int cb = c >> 2, q4 = c & 3;
            float4 p = *(const float4*)(Obuf + obase + (((c + lane) & 15) << 2));
            O[cb][q4 * 4 + 0] += p.x;
            O[cb][q4 * 4 + 1] += p.y;
            O[cb][q4 * 4 + 2] += p.z;
            O[cb][q4 * 4 + 3] += p.w;
        }
        const float inv = 1.0f / Lt;
        const float* Gb = Gw + ((size_t)b * kC + 4 * hh) * kN + n0 + qg * 32 + lq;
        float*       Ob = out + ((size_t)b * kC + 4 * hh) * kN + n0 + qg * 32 + lq;
        #pragma unroll
        for (int cb = 0; cb < 4; ++cb) {
            #pragma unroll
            for (int r = 0; r < 16; ++r) {
                const int coff = cb * 32 + (r & 3) + 8 * (r >> 2);  // + 4*hh in base
                Ob[(size_t)coff * kN] = O[cb][r] * inv * Gb[(size_t)coff * kN];
            }
        }
    }
}

// ---------------------------------------------------------------------------
extern "C" void kernel_launch(void* const* d_in, const int* in_sizes, int n_in,
                              void* d_out, int out_size, void* d_ws, size_t ws_size,
                              hipStream_t stream) {
    const float* tgt   = (const float*)d_in[0];
    const float* ref   = (const float*)d_in[1];
    const float* W_tgt = (const float*)d_in[2];
    const float* b_tgt = (const float*)d_in[3];
    const float* W_ref = (const float*)d_in[4];
    const float* b_ref = (const float*)d_in[5];
    const float* W_out = (const float*)d_in[6];
    const float* b_out = (const float*)d_in[7];
    float* out = (float*)d_out;

    const size_t QK = (size_t)8 * kN * kCH;              // fp16 -> 4 MB each
    const size_t CV = (size_t)8 * kC * kN;               // fp16 -> 8 MB
    unsigned short* Qw = (unsigned short*)d_ws;          // 4 MB
    unsigned short* Kw = Qw + QK;                        // 4 MB
    unsigned short* Vw = Kw + QK;                        // 8 MB
    float*          Gw = (float*)(Vw + CV);              // 16 MB (total 32 MB)

    proj_fused<<<dim3(32, 16), 256, 0, stream>>>(tgt, ref, W_tgt, W_ref, W_out,
                                                 b_tgt, b_ref, b_out, Qw, Kw, Vw, Gw);
    flash10_kernel<<<dim3(512), 256, 0, stream>>>(Qw, Kw, Vw, Gw, out);
}

// Round 8
// 182.100 us; speedup vs baseline: 1.1518x; 1.0239x over previous
//
#include <hip/hip_runtime.h>

typedef __attribute__((ext_vector_type(8))) _Float16 f16x8;   // 8 fp16 = 4 VGPRs
typedef __attribute__((ext_vector_type(4))) float f32x4;
typedef __attribute__((ext_vector_type(16))) float f32x16;

constexpr int kC  = 128;
constexpr int kCH = 64;
constexpr int kN  = 4096;
constexpr float kLog2e = 1.4426950408889634f;

__device__ __forceinline__ unsigned pkrtz(float a, float b) {
    union { __fp16 __attribute__((ext_vector_type(2))) v; unsigned u; } cv;
    cv.v = __builtin_amdgcn_cvt_pkrtz(a, b);
    return cv.u;
}

__device__ __forceinline__ float x2(float x) {        // bare v_exp_f32
    return __builtin_amdgcn_exp2f(x);
}

__device__ __forceinline__ float hadd2(unsigned u) {  // fp16 pair -> f32 sum
    union { unsigned v; _Float16 h[2]; } c; c.v = u;
    return (float)c.h[0] + (float)c.h[1];
}

// direct global->LDS DMA, 16B per lane, dest = wave-uniform base + lane*16
__device__ __forceinline__ void g2l16(const unsigned short* g, unsigned short* l) {
    __builtin_amdgcn_global_load_lds(
        (const __attribute__((address_space(1))) unsigned int*)(g),
        (__attribute__((address_space(3))) unsigned int*)(l),
        16, 0, 0);
}

// ---------------------------------------------------------------------------
// Fused projection — byte-identical to R4 (validated anchor). Two slices:
//   0: tgt -> Q,G   1: ref -> K,V. 2 token-tiles/block, LDS double-buffered.
// ---------------------------------------------------------------------------
__global__ __launch_bounds__(256, 2) void proj_fused(
    const float* __restrict__ tgt, const float* __restrict__ ref,
    const float* __restrict__ Wt, const float* __restrict__ Wr,
    const float* __restrict__ Wo, const float* __restrict__ bt,
    const float* __restrict__ br, const float* __restrict__ bo,
    unsigned short* __restrict__ Qw, unsigned short* __restrict__ Kw,
    unsigned short* __restrict__ Vw, float* __restrict__ Gw)
{
    __shared__ __align__(16) unsigned short Xs[2][64 * 128];   // 2 x 16KB
    const int t = threadIdx.x;
    const int sl2 = blockIdx.y >> 3;         // 0 = tgt (Q+G), 1 = ref (K+V)
    const int b = blockIdx.y & 7;
    const int tok0 = blockIdx.x << 7;        // 128 tokens per block (2 tiles)

    const int w = t >> 6, lane = t & 63;
    const int lg = (lane >> 4) & 3, lm = lane & 15;

    const float* X = sl2 ? ref : tgt;
    const float* Xb0 = X + ((size_t)b * kC) * kN + tok0;
    unsigned short* Vout = Vw + ((size_t)b * kC) * kN + tok0;

    const float* Wqk  = sl2 ? Wr : Wt;
    const float* bqk  = sl2 ? br : bt;
    const float scale = sl2 ? 1.0f : kLog2e;

    f16x8 wfq[4];
    float bq[4];
    {
        const int ocb = w * 16;
        #pragma unroll
        for (int ks = 0; ks < 4; ++ks) {
            const float* wp = Wqk + (size_t)(ocb + lm) * kC + ks * 32 + lg * 8;
            f32x4 f0 = *(const f32x4*)wp;
            f32x4 f1 = *(const f32x4*)(wp + 4);
            union { f16x8 h; uint4 u; } cv;
            cv.u = make_uint4(pkrtz(f0[0] * scale, f0[1] * scale),
                              pkrtz(f0[2] * scale, f0[3] * scale),
                              pkrtz(f1[0] * scale, f1[1] * scale),
                              pkrtz(f1[2] * scale, f1[3] * scale));
            wfq[ks] = cv.h;
        }
        #pragma unroll
        for (int r = 0; r < 4; ++r) bq[r] = bqk[ocb + lg * 4 + r] * scale;
    }

    f16x8 wfg[2][4];
    float bg[2][4];
    if (sl2 == 0) {
        const int ocb = w * 32;
        #pragma unroll
        for (int ot = 0; ot < 2; ++ot) {
            const int oc = ocb + ot * 16 + lm;
            #pragma unroll
            for (int ks = 0; ks < 4; ++ks) {
                const float* wp = Wo + (size_t)oc * kC + ks * 32 + lg * 8;
                f32x4 f0 = *(const f32x4*)wp;
                f32x4 f1 = *(const f32x4*)(wp + 4);
                union { f16x8 h; uint4 u; } cv;
                cv.u = make_uint4(pkrtz(f0[0], f0[1]), pkrtz(f0[2], f0[3]),
                                  pkrtz(f1[0], f1[1]), pkrtz(f1[2], f1[3]));
                wfg[ot][ks] = cv.h;
            }
            #pragma unroll
            for (int r = 0; r < 4; ++r) bg[ot][r] = bo[ocb + ot * 16 + lg * 4 + r];
        }
    }

    const int tk4 = (t & 15) * 4;
    const int c8  = (t >> 4) * 8;

    auto loadX = [&](int toff, f32x4* xv) {
        #pragma unroll
        for (int j = 0; j < 8; ++j)
            xv[j] = *(const f32x4*)(Xb0 + (size_t)(c8 + j) * kN + toff + tk4);
    };
    auto stageX = [&](const f32x4* xv, unsigned short* Xsb, int toff) {
        if (sl2 == 1) {
            #pragma unroll
            for (int j = 0; j < 8; ++j)
                *(uint2*)(Vout + (size_t)(c8 + j) * kN + toff + tk4) =
                    make_uint2(pkrtz(xv[j][0], xv[j][1]), pkrtz(xv[j][2], xv[j][3]));
        }
        #pragma unroll
        for (int s = 0; s < 4; ++s) {        // s STATIC (rule #20)
            const int tok = tk4 + s;
            const int cc = (c8 >> 3) ^ (tok & 7);
            uint4 pk;
            pk.x = pkrtz(xv[0][s], xv[1][s]);
            pk.y = pkrtz(xv[2][s], xv[3][s]);
            pk.z = pkrtz(xv[4][s], xv[5][s]);
            pk.w = pkrtz(xv[6][s], xv[7][s]);
            *(uint4*)(Xsb + tok * 128 + cc * 8) = pk;
        }
    };
    auto compute = [&](const unsigned short* Xsb, int tokb) {
        unsigned short* outp = (sl2 ? Kw : Qw) + ((size_t)b * kN + tokb) * kCH;
        float* Gb = Gw + ((size_t)b * kC) * kN + tokb;
        const int ocq = w * 16;
        const int ocg = w * 32;
        #pragma unroll
        for (int ns = 0; ns < 4; ++ns) {
            const int tok = ns * 16 + lm;
            f16x8 xf[4];
            #pragma unroll
            for (int ks = 0; ks < 4; ++ks)
                xf[ks] = *(const f16x8*)(Xsb + tok * 128 +
                                         (((ks * 4 + lg) ^ (tok & 7)) << 3));
            {
                f32x4 acc = {bq[0], bq[1], bq[2], bq[3]};
                #pragma unroll
                for (int ks = 0; ks < 4; ++ks)
                    acc = __builtin_amdgcn_mfma_f32_16x16x32_f16(wfq[ks], xf[ks], acc, 0, 0, 0);
                uint2 pk;
                pk.x = pkrtz(fmaxf(acc[0], 0.f), fmaxf(acc[1], 0.f));
                pk.y = pkrtz(fmaxf(acc[2], 0.f), fmaxf(acc[3], 0.f));
                *(uint2*)(outp + (size_t)tok * kCH + ocq + lg * 4) = pk;
            }
            if (sl2 == 0) {
                #pragma unroll
                for (int ot = 0; ot < 2; ++ot) {
                    f32x4 acc = {bg[ot][0], bg[ot][1], bg[ot][2], bg[ot][3]};
                    #pragma unroll
                    for (int ks = 0; ks < 4; ++ks)
                        acc = __builtin_amdgcn_mfma_f32_16x16x32_f16(wfg[ot][ks], xf[ks], acc, 0, 0, 0);
                    #pragma unroll
                    for (int r = 0; r < 4; ++r)
                        Gb[(size_t)(ocg + ot * 16 + lg * 4 + r) * kN + tok] = acc[r];
                }
            }
        }
    };

    f32x4 xv[8], xw[8];
    loadX(0, xv);
    stageX(xv, Xs[0], 0);
    __syncthreads();
    loadX(64, xw);
    compute(Xs[0], tok0);
    stageX(xw, Xs[1], 64);
    __syncthreads();
    compute(Xs[1], tok0 + 64);
}

// ---------------------------------------------------------------------------
// Flash attention R8 = R7's 32x32 split-K machine with two fixes:
//   (1) block mapping reverted to b = bx&7 (XCD j <-> batch j L2 affinity;
//       R7's batch-major remap thrashed L2: FETCH 16.4 -> 59.5 MB)
//   (2) defer-max rescale (T13, THR=8): O-rescale only when the running max
//       grows by >8 (P bounded by 2^8; L still sums the ROUNDED P).
// Layouts validated by R7 (absmax 0.0625).
// ---------------------------------------------------------------------------
__global__ __launch_bounds__(256, 2) void flash11_kernel(
    const unsigned short* __restrict__ Qw,   // [8][4096][64] fp16 (x log2e)
    const unsigned short* __restrict__ Kw,   // [8][4096][64] fp16
    const unsigned short* __restrict__ Vw,   // [8][128][4096] fp16
    const float* __restrict__ Gw,            // [8][128][4096] fp32 gate
    float* __restrict__ out)                 // [8][128][4096]
{
    __shared__ __align__(16) unsigned short Ks[2][64 * 64];    // 16KB
    __shared__ __align__(16) unsigned short Vs[2][128 * 64];   // 32KB
    __shared__ float2 mlb[4][32];                              // 1KB merge buf

    const int t = threadIdx.x;
    const int b  = blockIdx.x & 7;           // XCD j serves batch j
    const int n0 = (blockIdx.x >> 3) << 6;
    const int w = t >> 6, lane = t & 63;
    const int qg = w >> 1, kh = w & 1;       // q-group, key-half
    const int lq = lane & 31, hh = lane >> 5;
    const int n0q = n0 + qg * 32 + lq;       // this lane's q (global token)

    const unsigned short* Qb = Qw + ((size_t)b * kN + n0q) * kCH;
    const unsigned short* Kb = Kw + ((size_t)b * kN) * kCH;
    const unsigned short* Vb = Vw + ((size_t)b * kC) * kN;

    // Q B-frags: col=q (lane-resident), k(d) = st*16 + hh*8 + j
    f16x8 qf[4];
    #pragma unroll
    for (int st = 0; st < 4; ++st)
        qf[st] = *(const f16x8*)(Qb + st * 16 + hh * 8);

    // staging geometry (identical to flash7): linear LDS dest, XOR'd source
    const int srow = t >> 3, scol = t & 7;
    const int sco  = (scol ^ (srow & 7)) << 3;
    const int wv   = t >> 6;

    // fragment read addresses (swizzle involution matches staging)
    int ka[4];
    #pragma unroll
    for (int st = 0; st < 4; ++st)
        ka[st] = (kh * 32 + lq) * 64 + (((2 * st + hh) ^ (lq & 7)) << 3);
    int va[4][2];
    #pragma unroll
    for (int cb = 0; cb < 4; ++cb)
        #pragma unroll
        for (int s = 0; s < 2; ++s)
            va[cb][s] = (cb * 32 + lq) * 64 + (((kh * 4 + 2 * s + hh) ^ (lq & 7)) << 3);

    f32x16 O[4];
    #pragma unroll
    for (int cb = 0; cb < 4; ++cb)
        #pragma unroll
        for (int r = 0; r < 16; ++r) O[cb][r] = 0.f;
    float L = 0.f, m_run = 0.f;              // S >= 0 (relu inputs), exp2 domain

    unsigned short* Ks0 = Ks[0]; unsigned short* Ks1 = Ks[1];
    unsigned short* Vs0 = Vs[0]; unsigned short* Vs1 = Vs[1];

    auto stage = [&](unsigned short* Kd, unsigned short* Vd, int m0) {
        g2l16(Kb + (size_t)(m0 + srow) * kCH + sco,      Kd + wv * 512);
        g2l16(Kb + (size_t)(m0 + 32 + srow) * kCH + sco, Kd + 2048 + wv * 512);
        #pragma unroll
        for (int j = 0; j < 4; ++j)
            g2l16(Vb + (size_t)(32 * j + srow) * kN + m0 + sco,
                  Vd + j * 2048 + wv * 512);
    };
    stage(Ks0, Vs0, 0);                      // prologue: tile 0 -> buffer 0

    auto tile = [&](const unsigned short* Kc, const unsigned short* Vc,
                    unsigned short* Kn, unsigned short* Vn, int kt) {
        __syncthreads();                     // staged tile ready (vmcnt drained)
        if (kt + 1 < kN / 64) stage(Kn, Vn, (kt + 1) << 6);

        // ---- QK^T: S (32 keys x 32 q), keys = this wave's half ----
        f32x16 sa;
        #pragma unroll
        for (int r = 0; r < 16; ++r) sa[r] = 0.f;
        __builtin_amdgcn_s_setprio(1);
        #pragma unroll
        for (int st = 0; st < 4; ++st) {
            f16x8 kf = *(const f16x8*)(Kc + ka[st]);
            sa = __builtin_amdgcn_mfma_f32_32x32x16_f16(kf, qf[st], sa, 0, 0, 0);
        }
        __builtin_amdgcn_s_setprio(0);

        // ---- per-lane online softmax (lane owns one q-column) ----
        float mh = sa[0];
        #pragma unroll
        for (int r = 1; r < 16; ++r) mh = fmaxf(mh, sa[r]);
        const float mq = fmaxf(mh, __shfl_xor(mh, 32));
        // defer-max: only rescale when max grew by more than THR=8
        const bool resc = __any(mq > m_run + 8.0f);
        const float mnew = resc ? fmaxf(m_run, mq) : m_run;

        #pragma unroll
        for (int r = 0; r < 16; ++r) sa[r] = x2(sa[r] - mnew);
        unsigned P[8];
        #pragma unroll
        for (int i = 0; i < 8; ++i) P[i] = pkrtz(sa[2 * i], sa[2 * i + 1]);

        float ps = 0.f;                      // rowsum of fp16-ROUNDED P
        #pragma unroll
        for (int i = 0; i < 8; ++i) ps += hadd2(P[i]);
        ps += __shfl_xor(ps, 32);

        if (resc) {
            const float al = x2(m_run - mnew);
            #pragma unroll
            for (int cb = 0; cb < 4; ++cb) O[cb] *= al;
            L = L * al + ps;
            m_run = mnew;
        } else {
            L += ps;
        }

        // ---- in-register P relayout to B-frags (keys 16s..16s+15) ----
        f16x8 pf[2];
        #pragma unroll
        for (int s = 0; s < 2; ++s) {
            unsigned xa = __shfl_xor(P[4 * s + 0], 32);
            unsigned xb = __shfl_xor(P[4 * s + 1], 32);
            unsigned xc = __shfl_xor(P[4 * s + 2], 32);
            unsigned xd = __shfl_xor(P[4 * s + 3], 32);
            uint4 fu;
            fu.x = hh ? xc : P[4 * s + 0];
            fu.y = hh ? xd : P[4 * s + 1];
            fu.z = hh ? P[4 * s + 2] : xa;
            fu.w = hh ? P[4 * s + 3] : xb;
            union { uint4 u; f16x8 h; } cv; cv.u = fu;
            pf[s] = cv.h;
        }

        // ---- PV: O[cb] += V(32c x 16k) . P(16k x 32q) ----
        __builtin_amdgcn_s_setprio(1);
        #pragma unroll
        for (int cb = 0; cb < 4; ++cb) {
            #pragma unroll
            for (int s = 0; s < 2; ++s) {
                f16x8 vf = *(const f16x8*)(Vc + va[cb][s]);
                O[cb] = __builtin_amdgcn_mfma_f32_32x32x16_f16(vf, pf[s], O[cb], 0, 0, 0);
            }
        }
        __builtin_amdgcn_s_setprio(0);
    };

    for (int kt = 0; kt < kN / 64; kt += 2) {
        tile(Ks0, Vs0, Ks1, Vs1, kt);        // even: compute buf0, stage buf1
        tile(Ks1, Vs1, Ks0, Vs0, kt + 1);    // odd : compute buf1, stage buf0
    }

    // ---- epilogue: split-K merge across the wave pair, gate, store ----
    __syncthreads();
    mlb[w][lq] = make_float2(m_run, L);      // lanes lq and lq+32 write same val
    __syncthreads();
    const float2 pml = mlb[w ^ 1][lq];
    const float mt = fmaxf(m_run, pml.x);
    const float a  = x2(m_run - mt);
    const float Lt = L * a + pml.y * x2(pml.x - mt);

    float* Obuf = (float*)Vs;                // overlay dead V buffers (32KB)
    const int obase = qg * 4096 + lane * 64; // +rotation below: conflict-free
    #pragma unroll
    for (int cb = 0; cb < 4; ++cb) O[cb] *= a;

    if (kh) {                                // odd wave: publish scaled O
        #pragma unroll
        for (int c = 0; c < 16; ++c) {
            const int cb = c >> 2, q4 = c & 3;
            *(float4*)(Obuf + obase + (((c + lane) & 15) << 2)) =
                make_float4(O[cb][q4 * 4 + 0], O[cb][q4 * 4 + 1],
                            O[cb][q4 * 4 + 2], O[cb][q4 * 4 + 3]);
        }
    }
    __syncthreads();
    if (!kh) {                               // even wave: merge + gate + store
        #pragma unroll
        for (int c = 0; c < 16; ++c) {
            const int cb = c >> 2, q4 = c & 3;
            float4 p = *(const float4*)(Obuf + obase + (((c + lane) & 15) << 2));
            O[cb][q4 * 4 + 0] += p.x;
            O[cb][q4 * 4 + 1] += p.y;
            O[cb][q4 * 4 + 2] += p.z;
            O[cb][q4 * 4 + 3] += p.w;
        }
        const float inv = 1.0f / Lt;
        const float* Gb = Gw + ((size_t)b * kC + 4 * hh) * kN + n0 + qg * 32 + lq;
        float*       Ob = out + ((size_t)b * kC + 4 * hh) * kN + n0 + qg * 32 + lq;
        #pragma unroll
        for (int cb = 0; cb < 4; ++cb) {
            #pragma unroll
            for (int r = 0; r < 16; ++r) {
                const int coff = cb * 32 + (r & 3) + 8 * (r >> 2);  // + 4*hh in base
                Ob[(size_t)coff * kN] = O[cb][r] * inv * Gb[(size_t)coff * kN];
            }
        }
    }
}

// ---------------------------------------------------------------------------
extern "C" void kernel_launch(void* const* d_in, const int* in_sizes, int n_in,
                              void* d_out, int out_size, void* d_ws, size_t ws_size,
                              hipStream_t stream) {
    const float* tgt   = (const float*)d_in[0];
    const float* ref   = (const float*)d_in[1];
    const float* W_tgt = (const float*)d_in[2];
    const float* b_tgt = (const float*)d_in[3];
    const float* W_ref = (const float*)d_in[4];
    const float* b_ref = (const float*)d_in[5];
    const float* W_out = (const float*)d_in[6];
    const float* b_out = (const float*)d_in[7];
    float* out = (float*)d_out;

    const size_t QK = (size_t)8 * kN * kCH;              // fp16 -> 4 MB each
    const size_t CV = (size_t)8 * kC * kN;               // fp16 -> 8 MB
    unsigned short* Qw = (unsigned short*)d_ws;          // 4 MB
    unsigned short* Kw = Qw + QK;                        // 4 MB
    unsigned short* Vw = Kw + QK;                        // 8 MB
    float*          Gw = (float*)(Vw + CV);              // 16 MB (total 32 MB)

    proj_fused<<<dim3(32, 16), 256, 0, stream>>>(tgt, ref, W_tgt, W_ref, W_out,
                                                 b_tgt, b_ref, b_out, Qw, Kw, Vw, Gw);
    flash11_kernel<<<dim3(512), 256, 0, stream>>>(Qw, Kw, Vw, Gw, out);
}

// Round 9
// 174.564 us; speedup vs baseline: 1.2016x; 1.0432x over previous
//
#include <hip/hip_runtime.h>

typedef __attribute__((ext_vector_type(8))) _Float16 f16x8;   // 8 fp16 = 4 VGPRs
typedef __attribute__((ext_vector_type(4))) float f32x4;
typedef __attribute__((ext_vector_type(16))) float f32x16;
typedef __attribute__((ext_vector_type(2))) unsigned u32x2;

constexpr int kC  = 128;
constexpr int kCH = 64;
constexpr int kN  = 4096;
constexpr float kLog2e = 1.4426950408889634f;

__device__ __forceinline__ unsigned pkrtz(float a, float b) {
    union { __fp16 __attribute__((ext_vector_type(2))) v; unsigned u; } cv;
    cv.v = __builtin_amdgcn_cvt_pkrtz(a, b);
    return cv.u;
}

__device__ __forceinline__ float x2(float x) {        // bare v_exp_f32
    return __builtin_amdgcn_exp2f(x);
}

__device__ __forceinline__ float hadd2(unsigned u) {  // fp16 pair -> f32 sum
    union { unsigned v; _Float16 h[2]; } c; c.v = u;
    return (float)c.h[0] + (float)c.h[1];
}

// v_permlane32_swap: ret[0] = {A.lower, B.lower-as-upper}, ret[1] = {A.upper-as-lower, B.upper}
__device__ __forceinline__ u32x2 pl32(unsigned a, unsigned b) {
    return __builtin_amdgcn_permlane32_swap(a, b, false, false);
}
// xor-32 exchange of a scalar: needs DISTINCT physical regs (self-swap with an
// aliased reg would rotate, not exchange) -> early-clobber v_mov copy.
__device__ __forceinline__ u32x2 pl32x(float v) {
    float c;
    asm("v_mov_b32 %0, %1" : "=&v"(c) : "v"(v));
    union { float f; unsigned u; } a, b2; a.f = v; b2.f = c;
    return pl32(a.u, b2.u);
}
__device__ __forceinline__ float uf(unsigned u) {
    union { unsigned v; float f; } c; c.v = u; return c.f;
}

// direct global->LDS DMA, 16B per lane, dest = wave-uniform base + lane*16
__device__ __forceinline__ void g2l16(const unsigned short* g, unsigned short* l) {
    __builtin_amdgcn_global_load_lds(
        (const __attribute__((address_space(1))) unsigned int*)(g),
        (__attribute__((address_space(3))) unsigned int*)(l),
        16, 0, 0);
}

// ---------------------------------------------------------------------------
// Fused projection — byte-identical to R4 (validated anchor). Two slices:
//   0: tgt -> Q,G   1: ref -> K,V. 2 token-tiles/block, LDS double-buffered.
// ---------------------------------------------------------------------------
__global__ __launch_bounds__(256, 2) void proj_fused(
    const float* __restrict__ tgt, const float* __restrict__ ref,
    const float* __restrict__ Wt, const float* __restrict__ Wr,
    const float* __restrict__ Wo, const float* __restrict__ bt,
    const float* __restrict__ br, const float* __restrict__ bo,
    unsigned short* __restrict__ Qw, unsigned short* __restrict__ Kw,
    unsigned short* __restrict__ Vw, float* __restrict__ Gw)
{
    __shared__ __align__(16) unsigned short Xs[2][64 * 128];   // 2 x 16KB
    const int t = threadIdx.x;
    const int sl2 = blockIdx.y >> 3;         // 0 = tgt (Q+G), 1 = ref (K+V)
    const int b = blockIdx.y & 7;
    const int tok0 = blockIdx.x << 7;        // 128 tokens per block (2 tiles)

    const int w = t >> 6, lane = t & 63;
    const int lg = (lane >> 4) & 3, lm = lane & 15;

    const float* X = sl2 ? ref : tgt;
    const float* Xb0 = X + ((size_t)b * kC) * kN + tok0;
    unsigned short* Vout = Vw + ((size_t)b * kC) * kN + tok0;

    const float* Wqk  = sl2 ? Wr : Wt;
    const float* bqk  = sl2 ? br : bt;
    const float scale = sl2 ? 1.0f : kLog2e;

    f16x8 wfq[4];
    float bq[4];
    {
        const int ocb = w * 16;
        #pragma unroll
        for (int ks = 0; ks < 4; ++ks) {
            const float* wp = Wqk + (size_t)(ocb + lm) * kC + ks * 32 + lg * 8;
            f32x4 f0 = *(const f32x4*)wp;
            f32x4 f1 = *(const f32x4*)(wp + 4);
            union { f16x8 h; uint4 u; } cv;
            cv.u = make_uint4(pkrtz(f0[0] * scale, f0[1] * scale),
                              pkrtz(f0[2] * scale, f0[3] * scale),
                              pkrtz(f1[0] * scale, f1[1] * scale),
                              pkrtz(f1[2] * scale, f1[3] * scale));
            wfq[ks] = cv.h;
        }
        #pragma unroll
        for (int r = 0; r < 4; ++r) bq[r] = bqk[ocb + lg * 4 + r] * scale;
    }

    f16x8 wfg[2][4];
    float bg[2][4];
    if (sl2 == 0) {
        const int ocb = w * 32;
        #pragma unroll
        for (int ot = 0; ot < 2; ++ot) {
            const int oc = ocb + ot * 16 + lm;
            #pragma unroll
            for (int ks = 0; ks < 4; ++ks) {
                const float* wp = Wo + (size_t)oc * kC + ks * 32 + lg * 8;
                f32x4 f0 = *(const f32x4*)wp;
                f32x4 f1 = *(const f32x4*)(wp + 4);
                union { f16x8 h; uint4 u; } cv;
                cv.u = make_uint4(pkrtz(f0[0], f0[1]), pkrtz(f0[2], f0[3]),
                                  pkrtz(f1[0], f1[1]), pkrtz(f1[2], f1[3]));
                wfg[ot][ks] = cv.h;
            }
            #pragma unroll
            for (int r = 0; r < 4; ++r) bg[ot][r] = bo[ocb + ot * 16 + lg * 4 + r];
        }
    }

    const int tk4 = (t & 15) * 4;
    const int c8  = (t >> 4) * 8;

    auto loadX = [&](int toff, f32x4* xv) {
        #pragma unroll
        for (int j = 0; j < 8; ++j)
            xv[j] = *(const f32x4*)(Xb0 + (size_t)(c8 + j) * kN + toff + tk4);
    };
    auto stageX = [&](const f32x4* xv, unsigned short* Xsb, int toff) {
        if (sl2 == 1) {
            #pragma unroll
            for (int j = 0; j < 8; ++j)
                *(uint2*)(Vout + (size_t)(c8 + j) * kN + toff + tk4) =
                    make_uint2(pkrtz(xv[j][0], xv[j][1]), pkrtz(xv[j][2], xv[j][3]));
        }
        #pragma unroll
        for (int s = 0; s < 4; ++s) {        // s STATIC (rule #20)
            const int tok = tk4 + s;
            const int cc = (c8 >> 3) ^ (tok & 7);
            uint4 pk;
            pk.x = pkrtz(xv[0][s], xv[1][s]);
            pk.y = pkrtz(xv[2][s], xv[3][s]);
            pk.z = pkrtz(xv[4][s], xv[5][s]);
            pk.w = pkrtz(xv[6][s], xv[7][s]);
            *(uint4*)(Xsb + tok * 128 + cc * 8) = pk;
        }
    };
    auto compute = [&](const unsigned short* Xsb, int tokb) {
        unsigned short* outp = (sl2 ? Kw : Qw) + ((size_t)b * kN + tokb) * kCH;
        float* Gb = Gw + ((size_t)b * kC) * kN + tokb;
        const int ocq = w * 16;
        const int ocg = w * 32;
        #pragma unroll
        for (int ns = 0; ns < 4; ++ns) {
            const int tok = ns * 16 + lm;
            f16x8 xf[4];
            #pragma unroll
            for (int ks = 0; ks < 4; ++ks)
                xf[ks] = *(const f16x8*)(Xsb + tok * 128 +
                                         (((ks * 4 + lg) ^ (tok & 7)) << 3));
            {
                f32x4 acc = {bq[0], bq[1], bq[2], bq[3]};
                #pragma unroll
                for (int ks = 0; ks < 4; ++ks)
                    acc = __builtin_amdgcn_mfma_f32_16x16x32_f16(wfq[ks], xf[ks], acc, 0, 0, 0);
                uint2 pk;
                pk.x = pkrtz(fmaxf(acc[0], 0.f), fmaxf(acc[1], 0.f));
                pk.y = pkrtz(fmaxf(acc[2], 0.f), fmaxf(acc[3], 0.f));
                *(uint2*)(outp + (size_t)tok * kCH + ocq + lg * 4) = pk;
            }
            if (sl2 == 0) {
                #pragma unroll
                for (int ot = 0; ot < 2; ++ot) {
                    f32x4 acc = {bg[ot][0], bg[ot][1], bg[ot][2], bg[ot][3]};
                    #pragma unroll
                    for (int ks = 0; ks < 4; ++ks)
                        acc = __builtin_amdgcn_mfma_f32_16x16x32_f16(wfg[ot][ks], xf[ks], acc, 0, 0, 0);
                    #pragma unroll
                    for (int r = 0; r < 4; ++r)
                        Gb[(size_t)(ocg + ot * 16 + lg * 4 + r) * kN + tok] = acc[r];
                }
            }
        }
    };

    f32x4 xv[8], xw[8];
    loadX(0, xv);
    stageX(xv, Xs[0], 0);
    __syncthreads();
    loadX(64, xw);
    compute(Xs[0], tok0);
    stageX(xw, Xs[1], 64);
    __syncthreads();
    compute(Xs[1], tok0 + 64);
}

// ---------------------------------------------------------------------------
// Flash attention R9 = flash11's 32x32 split-K machine + two latency fixes:
//   (1) T12: all xor-32 exchanges via v_permlane32_swap (VALU, ~4cyc) instead
//       of ds_bpermute (~120cyc). P-relay = 4 swaps (each swap's two outputs
//       are exactly the two needed fragment words).
//   (2) T15: lagged PV — P(t) kept in registers, PV(t-1) runs during tile t
//       interleaved with softmax(t)'s exp/pack under the MFMA shadow.
//       V triple-buffered (WAR-safe across the barrier); operation order on
//       O (...PV(t-1), alpha_t, PV(t)...) identical to flash11 -> bit-same.
// ---------------------------------------------------------------------------
__global__ __launch_bounds__(256, 2) void flash12_kernel(
    const unsigned short* __restrict__ Qw,   // [8][4096][64] fp16 (x log2e)
    const unsigned short* __restrict__ Kw,   // [8][4096][64] fp16
    const unsigned short* __restrict__ Vw,   // [8][128][4096] fp16
    const float* __restrict__ Gw,            // [8][128][4096] fp32 gate
    float* __restrict__ out)                 // [8][128][4096]
{
    __shared__ __align__(16) unsigned short Ks[2][64 * 64];    // 16KB
    __shared__ __align__(16) unsigned short Vs[3][128 * 64];   // 48KB
    __shared__ float2 mlb[4][32];                              // 1KB merge buf

    const int t = threadIdx.x;
    const int b  = blockIdx.x & 7;           // XCD j serves batch j
    const int n0 = (blockIdx.x >> 3) << 6;
    const int w = t >> 6, lane = t & 63;
    const int qg = w >> 1, kh = w & 1;       // q-group, key-half
    const int lq = lane & 31, hh = lane >> 5;
    const int n0q = n0 + qg * 32 + lq;

    const unsigned short* Qb = Qw + ((size_t)b * kN + n0q) * kCH;
    const unsigned short* Kb = Kw + ((size_t)b * kN) * kCH;
    const unsigned short* Vb = Vw + ((size_t)b * kC) * kN;

    f16x8 qf[4];
    #pragma unroll
    for (int st = 0; st < 4; ++st)
        qf[st] = *(const f16x8*)(Qb + st * 16 + hh * 8);

    const int srow = t >> 3, scol = t & 7;
    const int sco  = (scol ^ (srow & 7)) << 3;
    const int wv   = t >> 6;

    int ka[4];
    #pragma unroll
    for (int st = 0; st < 4; ++st)
        ka[st] = (kh * 32 + lq) * 64 + (((2 * st + hh) ^ (lq & 7)) << 3);
    int va[4][2];
    #pragma unroll
    for (int cb = 0; cb < 4; ++cb)
        #pragma unroll
        for (int s = 0; s < 2; ++s)
            va[cb][s] = (cb * 32 + lq) * 64 + (((kh * 4 + 2 * s + hh) ^ (lq & 7)) << 3);

    f32x16 O[4];
    #pragma unroll
    for (int cb = 0; cb < 4; ++cb)
        #pragma unroll
        for (int r = 0; r < 16; ++r) O[cb][r] = 0.f;
    float L = 0.f, m_run = 0.f;              // S >= 0 (relu inputs), exp2 domain

    f16x8 pfp[2];                            // previous tile's P fragments
    {
        union { uint4 u; f16x8 h; } z;
        z.u = make_uint4(0u, 0u, 0u, 0u);
        pfp[0] = z.h; pfp[1] = z.h;
    }

    auto stage = [&](unsigned short* Kd, unsigned short* Vd, int m0) {
        g2l16(Kb + (size_t)(m0 + srow) * kCH + sco,      Kd + wv * 512);
        g2l16(Kb + (size_t)(m0 + 32 + srow) * kCH + sco, Kd + 2048 + wv * 512);
        #pragma unroll
        for (int j = 0; j < 4; ++j)
            g2l16(Vb + (size_t)(32 * j + srow) * kN + m0 + sco,
                  Vd + j * 2048 + wv * 512);
    };

    unsigned short *Kt = Ks[0], *Kn = Ks[1];
    unsigned short *Vp = Vs[2], *Vt = Vs[0], *Vn = Vs[1];
    stage(Kt, Vt, 0);                        // prologue: tile 0

    for (int kt = 0; kt < kN / 64; ++kt) {
        __syncthreads();                     // staged tile kt ready
        if (kt + 1 < kN / 64) stage(Kn, Vn, (kt + 1) << 6);

        // ---- QK^T: S (32 keys x 32 q), keys = this wave's half ----
        f32x16 sa;
        #pragma unroll
        for (int r = 0; r < 16; ++r) sa[r] = 0.f;
        __builtin_amdgcn_s_setprio(1);
        #pragma unroll
        for (int st = 0; st < 4; ++st) {
            f16x8 kf = *(const f16x8*)(Kt + ka[st]);
            sa = __builtin_amdgcn_mfma_f32_32x32x16_f16(kf, qf[st], sa, 0, 0, 0);
        }
        __builtin_amdgcn_s_setprio(0);

        // ---- max (permlane swap, no LDS) ----
        float mh = sa[0];
        #pragma unroll
        for (int r = 1; r < 16; ++r) mh = fmaxf(mh, sa[r]);
        u32x2 mr = pl32x(mh);
        const float mq = fmaxf(uf(mr[0]), uf(mr[1]));
        const bool resc = __any(mq > m_run + 8.0f);   // defer-max THR=8
        const float mnew = resc ? fmaxf(m_run, mq) : m_run;

        // ---- PV(t-1): independent of softmax(t); its MFMA shadow covers
        //      the exp/pack VALU below ----
        __builtin_amdgcn_s_setprio(1);
        if (kt > 0) {
            #pragma unroll
            for (int cb = 0; cb < 4; ++cb) {
                #pragma unroll
                for (int s = 0; s < 2; ++s) {
                    f16x8 vf = *(const f16x8*)(Vp + va[cb][s]);
                    O[cb] = __builtin_amdgcn_mfma_f32_32x32x16_f16(vf, pfp[s], O[cb], 0, 0, 0);
                }
            }
        }
        __builtin_amdgcn_s_setprio(0);

        // ---- exp / pack / rowsum (of fp16-ROUNDED P) ----
        #pragma unroll
        for (int r = 0; r < 16; ++r) sa[r] = x2(sa[r] - mnew);
        unsigned P[8];
        #pragma unroll
        for (int i = 0; i < 8; ++i) P[i] = pkrtz(sa[2 * i], sa[2 * i + 1]);
        float ps = 0.f;
        #pragma unroll
        for (int i = 0; i < 8; ++i) ps += hadd2(P[i]);
        u32x2 pr = pl32x(ps);
        ps = uf(pr[0]) + uf(pr[1]);

        if (resc) {                          // after PV(t-1): P(t-1) was at old scale
            const float al = x2(m_run - mnew);
            #pragma unroll
            for (int cb = 0; cb < 4; ++cb) O[cb] *= al;
            L = L * al + ps;
            m_run = mnew;
        } else {
            L += ps;
        }

        // ---- P relayout -> pfp for NEXT tile (4 permlane swaps total) ----
        #pragma unroll
        for (int s = 0; s < 2; ++s) {
            u32x2 r0 = pl32(P[4 * s + 0], P[4 * s + 2]);  // -> fu.x, fu.z
            u32x2 r1 = pl32(P[4 * s + 1], P[4 * s + 3]);  // -> fu.y, fu.w
            union { uint4 u; f16x8 h; } cv;
            cv.u = make_uint4(r0[0], r1[0], r0[1], r1[1]);
            pfp[s] = cv.h;
        }

        // ---- rotate buffers: V mod-3, K mod-2 ----
        unsigned short* tv = Vp; Vp = Vt; Vt = Vn; Vn = tv;
        unsigned short* tk = Kt; Kt = Kn; Kn = tk;
    }

    // ---- final PV (tile kN/64-1) ----
    __builtin_amdgcn_s_setprio(1);
    #pragma unroll
    for (int cb = 0; cb < 4; ++cb) {
        #pragma unroll
        for (int s = 0; s < 2; ++s) {
            f16x8 vf = *(const f16x8*)(Vp + va[cb][s]);
            O[cb] = __builtin_amdgcn_mfma_f32_32x32x16_f16(vf, pfp[s], O[cb], 0, 0, 0);
        }
    }
    __builtin_amdgcn_s_setprio(0);

    // ---- epilogue: split-K merge across the wave pair, gate, store ----
    __syncthreads();
    mlb[w][lq] = make_float2(m_run, L);
    __syncthreads();
    const float2 pml = mlb[w ^ 1][lq];
    const float mt = fmaxf(m_run, pml.x);
    const float a  = x2(m_run - mt);
    const float Lt = L * a + pml.y * x2(pml.x - mt);

    float* Obuf = (float*)Vs;                // overlay dead V buffers
    const int obase = qg * 4096 + lane * 64;
    #pragma unroll
    for (int cb = 0; cb < 4; ++cb) O[cb] *= a;

    if (kh) {                                // odd wave: publish scaled O
        #pragma unroll
        for (int c = 0; c < 16; ++c) {
            const int cb = c >> 2, q4 = c & 3;
            *(float4*)(Obuf + obase + (((c + lane) & 15) << 2)) =
                make_float4(O[cb][q4 * 4 + 0], O[cb][q4 * 4 + 1],
                            O[cb][q4 * 4 + 2], O[cb][q4 * 4 + 3]);
        }
    }
    __syncthreads();
    if (!kh) {                               // even wave: merge + gate + store
        #pragma unroll
        for (int c = 0; c < 16; ++c) {
            const int cb = c >> 2, q4 = c & 3;
            float4 p = *(const float4*)(Obuf + obase + (((c + lane) & 15) << 2));
            O[cb][q4 * 4 + 0] += p.x;
            O[cb][q4 * 4 + 1] += p.y;
            O[cb][q4 * 4 + 2] += p.z;
            O[cb][q4 * 4 + 3] += p.w;
        }
        const float inv = 1.0f / Lt;
        const float* Gb = Gw + ((size_t)b * kC + 4 * hh) * kN + n0 + qg * 32 + lq;
        float*       Ob = out + ((size_t)b * kC + 4 * hh) * kN + n0 + qg * 32 + lq;
        #pragma unroll
        for (int cb = 0; cb < 4; ++cb) {
            #pragma unroll
            for (int r = 0; r < 16; ++r) {
                const int coff = cb * 32 + (r & 3) + 8 * (r >> 2);
                Ob[(size_t)coff * kN] = O[cb][r] * inv * Gb[(size_t)coff * kN];
            }
        }
    }
}

// ---------------------------------------------------------------------------
extern "C" void kernel_launch(void* const* d_in, const int* in_sizes, int n_in,
                              void* d_out, int out_size, void* d_ws, size_t ws_size,
                              hipStream_t stream) {
    const float* tgt   = (const float*)d_in[0];
    const float* ref   = (const float*)d_in[1];
    const float* W_tgt = (const float*)d_in[2];
    const float* b_tgt = (const float*)d_in[3];
    const float* W_ref = (const float*)d_in[4];
    const float* b_ref = (const float*)d_in[5];
    const float* W_out = (const float*)d_in[6];
    const float* b_out = (const float*)d_in[7];
    float* out = (float*)d_out;

    const size_t QK = (size_t)8 * kN * kCH;              // fp16 -> 4 MB each
    const size_t CV = (size_t)8 * kC * kN;               // fp16 -> 8 MB
    unsigned short* Qw = (unsigned short*)d_ws;          // 4 MB
    unsigned short* Kw = Qw + QK;                        // 4 MB
    unsigned short* Vw = Kw + QK;                        // 8 MB
    float*          Gw = (float*)(Vw + CV);              // 16 MB (total 32 MB)

    proj_fused<<<dim3(32, 16), 256, 0, stream>>>(tgt, ref, W_tgt, W_ref, W_out,
                                                 b_tgt, b_ref, b_out, Qw, Kw, Vw, Gw);
    flash12_kernel<<<dim3(512), 256, 0, stream>>>(Qw, Kw, Vw, Gw, out);
}